// Round 11
// baseline (2296.582 us; speedup 1.0000x reference)
//
#include <hip/hip_runtime.h>
#include <hip/hip_bf16.h>

#define NL 10000
#define NP 100000
#define PLEN 8
#define H 32
#define NROUNDS 8
#define E_TOT (NP * PLEN)

typedef float f2 __attribute__((ext_vector_type(2)));
typedef float f4 __attribute__((ext_vector_type(4)));
typedef short bh8 __attribute__((ext_vector_type(8)));

// ---------- ws layout (float offsets) ----------
#define LINK_OFF   0          // 320000 fp32 link_state
#define PATH_OFF   320000     // 3200000
#define AGG_OFF    3520000    // 320000: gather mode reuses as LHI(160000)+LLO(160000)
#define WTS_OFF    3840000    // 13345 fp32 weights
#define PW_OFF     3853400    // 8 regions x 1600 floats (ushort[3072] each)
#define FLAG_OFF   3869000
#define INT_OFF    3870000    // ints: counts | offsets@10000 | cursor@20016 | perm@30016 (800000)
#define HS_OFF     4700032
#define WS_NEED_FLOATS (HS_OFF + (size_t)E_TOT * H)

#define LOG2E 1.44269504f

__device__ __forceinline__ float bf2f(unsigned short u) {
  union { unsigned int i; float f; } v; v.i = ((unsigned int)u) << 16; return v.f;
}
__device__ __forceinline__ float fast_exp2(float x) {
#if __has_builtin(__builtin_amdgcn_exp2f)
  return __builtin_amdgcn_exp2f(x);
#else
  return __expf(x * 0.69314718f);
#endif
}
__device__ __forceinline__ float fast_rcp(float x) {
#if __has_builtin(__builtin_amdgcn_rcpf)
  return __builtin_amdgcn_rcpf(x);
#else
  return 1.f / x;
#endif
}
__device__ __forceinline__ float fast_sigm(float x) {
  return fast_rcp(1.f + fast_exp2(-LOG2E * x));
}
__device__ __forceinline__ float fast_tanh2(float x) {
  return 1.f - 2.f * fast_rcp(1.f + fast_exp2((2.f * LOG2E) * x));
}
__device__ __forceinline__ float loadf(const void* p, long i, bool bf) {
  return bf ? bf2f(((const unsigned short*)p)[i]) : ((const float*)p)[i];
}

// split 8 fp32 into bf16 hi + bf16 lo (residual), trunc rounding
__device__ __forceinline__ void split8(f4 a, f4 b, bh8& hi, bh8& lo) {
  #pragma unroll
  for (int i = 0; i < 4; ++i) {
    unsigned ua = __float_as_uint(a[i]);
    float hfa = __uint_as_float(ua & 0xffff0000u);
    hi[i] = (short)(ua >> 16);
    lo[i] = (short)(__float_as_uint(a[i] - hfa) >> 16);
    unsigned ub = __float_as_uint(b[i]);
    float hfb = __uint_as_float(ub & 0xffff0000u);
    hi[4 + i] = (short)(ub >> 16);
    lo[4 + i] = (short)(__float_as_uint(b[i] - hfb) >> 16);
  }
}

// ---------- dtype probe ----------
__global__ void probe_dtype(const unsigned int* __restrict__ cap_words,
                            int* __restrict__ flag) {
  int lane = threadIdx.x;
  int c = 0;
  #pragma unroll
  for (int i = 0; i < 4; ++i) {
    unsigned int b = (cap_words[lane * 4 + i] >> 8) & 0xFF;
    if (b >= 0x30 && b < 0x40) ++c;
  }
  #pragma unroll
  for (int d = 32; d > 0; d >>= 1) c += __shfl_down(c, d);
  if (lane == 0) *flag = (c > 128) ? 1 : 0;
}

// ---------- scalar GRU cell (fallback path only) ----------
__device__ __forceinline__ void gru_cell_f2(const float* __restrict__ W,
                                            const f2 x[16], f2 h[16]) {
  const f2* Wih = (const f2*)W;
  const f2* Whh = (const f2*)(W + 3072);
  const float* bih = W + 6144;
  const float* bhh = W + 6240;
  f2 hn[16];
  #pragma unroll
  for (int jj = 0; jj < 16; ++jj) {
    #pragma unroll
    for (int s = 0; s < 2; ++s) {
      const int j = 2 * jj + s;
      f2 ar = {0.f, 0.f}, az = {0.f, 0.f}, an = {0.f, 0.f}, ah = {0.f, 0.f};
      #pragma unroll
      for (int k = 0; k < 16; ++k) {
        ar = __builtin_elementwise_fma(Wih[j * 16 + k], x[k], ar);
        ar = __builtin_elementwise_fma(Whh[j * 16 + k], h[k], ar);
        az = __builtin_elementwise_fma(Wih[(H + j) * 16 + k], x[k], az);
        az = __builtin_elementwise_fma(Whh[(H + j) * 16 + k], h[k], az);
        an = __builtin_elementwise_fma(Wih[(2 * H + j) * 16 + k], x[k], an);
        ah = __builtin_elementwise_fma(Whh[(2 * H + j) * 16 + k], h[k], ah);
      }
      float r = fast_sigm(ar.x + ar.y + bih[j] + bhh[j]);
      float z = fast_sigm(az.x + az.y + bih[H + j] + bhh[H + j]);
      float n = fast_tanh2(an.x + an.y + bih[2 * H + j] +
                           r * (ah.x + ah.y + bhh[2 * H + j]));
      float hold = (s == 0) ? h[jj].x : h[jj].y;
      float hv = n + z * (hold - n);
      if (s == 0) hn[jj].x = hv; else hn[jj].y = hv;
    }
  }
  #pragma unroll
  for (int k = 0; k < 16; ++k) h[k] = hn[k];
}

// ---------- weight conversion (+ hi/lo bf16 splits of all 4 GRU matrices) ----------
struct BfSeg { const void* src; int dstoff; int len; };
struct BfSegs { BfSeg s[14]; };
struct WPack { unsigned short* p[8]; };

__global__ void convert_weights(BfSegs segs, WPack wp, const int* __restrict__ flag,
                                float* __restrict__ dst) {
  const bool bf = (*flag != 0);
  const int si = blockIdx.x;
  const void* p = segs.s[si].src;
  const int off = segs.s[si].dstoff, len = segs.s[si].len;
  int hix = -1;
  if (si == 0) hix = 0; else if (si == 1) hix = 2;
  else if (si == 4) hix = 4; else if (si == 5) hix = 6;
  for (int i = threadIdx.x; i < len; i += blockDim.x) {
    float f = loadf(p, i, bf);
    dst[off + i] = f;
    if (hix >= 0) {
      unsigned u = __float_as_uint(f);
      float fh = __uint_as_float(u & 0xffff0000u);
      wp.p[hix][i] = (unsigned short)(u >> 16);
      wp.p[hix + 1][i] = (unsigned short)(__float_as_uint(f - fh) >> 16);
    }
  }
}

__global__ void init_states(const void* __restrict__ cap,
                            const void* __restrict__ bw,
                            const int* __restrict__ flag,
                            float* __restrict__ link_state,
                            unsigned short* __restrict__ lhi,
                            unsigned short* __restrict__ llo,
                            float* __restrict__ path_state) {
  const bool bf = (*flag != 0);
  int i = blockIdx.x * blockDim.x + threadIdx.x;
  if (i < NP * H) path_state[i] = ((i & (H - 1)) == 0) ? loadf(bw, i >> 5, bf) : 0.f;
  if (i < NL * H) {
    float v = ((i & (H - 1)) == 0) ? loadf(cap, i >> 5, bf) : 0.f;
    link_state[i] = v;
    unsigned u = __float_as_uint(v);
    float fh = __uint_as_float(u & 0xffff0000u);
    lhi[i] = (unsigned short)(u >> 16);
    llo[i] = (unsigned short)(__float_as_uint(v - fh) >> 16);
  }
}

// ---------- CSR build ----------
__global__ void csr_count(const int* __restrict__ links, int* __restrict__ counts) {
  int e = blockIdx.x * blockDim.x + threadIdx.x;
  if (e < E_TOT) atomicAdd(&counts[links[e]], 1);
}

__global__ __launch_bounds__(256) void csr_scan(const int* __restrict__ counts,
                                                int* __restrict__ offsets,
                                                int* __restrict__ cursor) {
  __shared__ int part[256];
  const int t = threadIdx.x;
  const int base = t * 40;
  int s = 0;
  for (int i = 0; i < 40; ++i) {
    int idx = base + i;
    if (idx < NL) s += counts[idx];
  }
  part[t] = s;
  __syncthreads();
  for (int d = 1; d < 256; d <<= 1) {
    int v = (t >= d) ? part[t - d] : 0;
    __syncthreads();
    part[t] += v;
    __syncthreads();
  }
  int run = (t > 0) ? part[t - 1] : 0;
  for (int i = 0; i < 40; ++i) {
    int idx = base + i;
    if (idx < NL) {
      offsets[idx] = run;
      cursor[idx] = run;
      run += counts[idx];
    }
  }
  if (t == 255) offsets[NL] = run;
}

// perm[e] = CSR slot of edge e — path kernel scatters messages into CSR order
__global__ void csr_fill(const int* __restrict__ links, int* __restrict__ cursor,
                         int* __restrict__ perm) {
  int e = blockIdx.x * blockDim.x + threadIdx.x;
  if (e < E_TOT) {
    int l = links[e];
    int pos = atomicAdd(&cursor[l], 1);
    perm[e] = pos;
  }
}

// ---------- MFMA path round: block=256 = 4 waves, each wave = 16 paths ----------
// fp32-exact via hi/lo splits of BOTH weights and states (lo*lo dropped ~2^-17).
// Last round (store_msgs==0): fused readout MLP, no path_state write, no hs write.
__global__ __launch_bounds__(256, 5) void path_round_mfma(
    const int* __restrict__ links, const int* __restrict__ perm,
    const unsigned short* __restrict__ lhi, const unsigned short* __restrict__ llo,
    float* __restrict__ path_state, float* __restrict__ hs,
    const float* __restrict__ W,
    const unsigned short* __restrict__ wih_hi, const unsigned short* __restrict__ wih_lo,
    const unsigned short* __restrict__ whh_hi, const unsigned short* __restrict__ whh_lo,
    const int* __restrict__ flag, void* __restrict__ out,
    int store_msgs) {
  __shared__ float lds_all[4 * 16 * 36];
  const int wv = threadIdx.x >> 6;
  const int tile = blockIdx.x * 4 + wv;
  if (tile >= NP / 16) return;
  const int p0 = tile * 16;
  const int lane = threadIdx.x & 63;
  const int c = lane & 15, q = lane >> 4, m = c;
  float* lds = lds_all + wv * (16 * 36);

  bh8 wihH[6], wihL[6], whhH[6], whhL[6];
  #pragma unroll
  for (int tn = 0; tn < 6; ++tn) {
    size_t o = (size_t)(tn * 16 + c) * H + q * 8;
    wihH[tn] = *(const bh8*)(wih_hi + o);
    wihL[tn] = *(const bh8*)(wih_lo + o);
    whhH[tn] = *(const bh8*)(whh_hi + o);
    whhL[tn] = *(const bh8*)(whh_lo + o);
  }
  const float* bih = W + 6144;
  const float* bhh = W + 6240;
  float b_r[2], b_z[2], b_in[2], b_hn[2];
  #pragma unroll
  for (int u2 = 0; u2 < 2; ++u2) {
    int u = u2 * 16 + c;
    b_r[u2] = bih[u] + bhh[u];
    b_z[u2] = bih[32 + u] + bhh[32 + u];
    b_in[u2] = bih[64 + u];
    b_hn[u2] = bhh[64 + u];
  }
  float hC[2][4];
  #pragma unroll
  for (int u2 = 0; u2 < 2; ++u2)
    #pragma unroll
    for (int rg = 0; rg < 4; ++rg)
      hC[u2][rg] = path_state[(size_t)(p0 + q * 4 + rg) * H + u2 * 16 + c];
  f4 hfa = *(const f4*)(path_state + (size_t)(p0 + m) * H + q * 8);
  f4 hfb = *(const f4*)(path_state + (size_t)(p0 + m) * H + q * 8 + 4);
  bh8 hhi, hlo;
  split8(hfa, hfb, hhi, hlo);
  int lk[PLEN], pm[PLEN];
  {
    const int4* lp = (const int4*)(links + (size_t)(p0 + m) * PLEN);
    int4 a = lp[0], b = lp[1];
    lk[0] = a.x; lk[1] = a.y; lk[2] = a.z; lk[3] = a.w;
    lk[4] = b.x; lk[5] = b.y; lk[6] = b.z; lk[7] = b.w;
    const int4* qp = (const int4*)(perm + (size_t)(p0 + m) * PLEN);
    int4 e = qp[0], f = qp[1];
    pm[0] = e.x; pm[1] = e.y; pm[2] = e.z; pm[3] = e.w;
    pm[4] = f.x; pm[5] = f.y; pm[6] = f.z; pm[7] = f.w;
  }
  bh8 xhi = *(const bh8*)(lhi + (size_t)lk[0] * H + q * 8);
  bh8 xlo = *(const bh8*)(llo + (size_t)lk[0] * H + q * 8);
  const f4 z4 = {0.f, 0.f, 0.f, 0.f};

  #pragma unroll 1
  for (int t = 0; t < PLEN; ++t) {
    bh8 xnhi, xnlo;
    if (t + 1 < PLEN) {
      xnhi = *(const bh8*)(lhi + (size_t)lk[t + 1] * H + q * 8);
      xnlo = *(const bh8*)(llo + (size_t)lk[t + 1] * H + q * 8);
    }
    f4 aR[2], aZ[2], aI[2], aHn[2];
    #pragma unroll
    for (int u2 = 0; u2 < 2; ++u2) {
      f4 a = z4;
      a = __builtin_amdgcn_mfma_f32_16x16x32_bf16(xhi, wihH[u2], a, 0, 0, 0);
      a = __builtin_amdgcn_mfma_f32_16x16x32_bf16(hhi, whhH[u2], a, 0, 0, 0);
      a = __builtin_amdgcn_mfma_f32_16x16x32_bf16(xlo, wihH[u2], a, 0, 0, 0);
      a = __builtin_amdgcn_mfma_f32_16x16x32_bf16(hlo, whhH[u2], a, 0, 0, 0);
      a = __builtin_amdgcn_mfma_f32_16x16x32_bf16(xhi, wihL[u2], a, 0, 0, 0);
      a = __builtin_amdgcn_mfma_f32_16x16x32_bf16(hhi, whhL[u2], a, 0, 0, 0);
      aR[u2] = a;
      f4 b = z4;
      b = __builtin_amdgcn_mfma_f32_16x16x32_bf16(xhi, wihH[2 + u2], b, 0, 0, 0);
      b = __builtin_amdgcn_mfma_f32_16x16x32_bf16(hhi, whhH[2 + u2], b, 0, 0, 0);
      b = __builtin_amdgcn_mfma_f32_16x16x32_bf16(xlo, wihH[2 + u2], b, 0, 0, 0);
      b = __builtin_amdgcn_mfma_f32_16x16x32_bf16(hlo, whhH[2 + u2], b, 0, 0, 0);
      b = __builtin_amdgcn_mfma_f32_16x16x32_bf16(xhi, wihL[2 + u2], b, 0, 0, 0);
      b = __builtin_amdgcn_mfma_f32_16x16x32_bf16(hhi, whhL[2 + u2], b, 0, 0, 0);
      aZ[u2] = b;
      f4 ci = z4;
      ci = __builtin_amdgcn_mfma_f32_16x16x32_bf16(xhi, wihH[4 + u2], ci, 0, 0, 0);
      ci = __builtin_amdgcn_mfma_f32_16x16x32_bf16(xlo, wihH[4 + u2], ci, 0, 0, 0);
      ci = __builtin_amdgcn_mfma_f32_16x16x32_bf16(xhi, wihL[4 + u2], ci, 0, 0, 0);
      aI[u2] = ci;
      f4 ch = z4;
      ch = __builtin_amdgcn_mfma_f32_16x16x32_bf16(hhi, whhH[4 + u2], ch, 0, 0, 0);
      ch = __builtin_amdgcn_mfma_f32_16x16x32_bf16(hlo, whhH[4 + u2], ch, 0, 0, 0);
      ch = __builtin_amdgcn_mfma_f32_16x16x32_bf16(hhi, whhL[4 + u2], ch, 0, 0, 0);
      aHn[u2] = ch;
    }
    #pragma unroll
    for (int u2 = 0; u2 < 2; ++u2)
      #pragma unroll
      for (int rg = 0; rg < 4; ++rg) {
        float rr = fast_sigm(aR[u2][rg] + b_r[u2]);
        float zz = fast_sigm(aZ[u2][rg] + b_z[u2]);
        float nn = fast_tanh2(fmaf(rr, aHn[u2][rg] + b_hn[u2], aI[u2][rg] + b_in[u2]));
        float hv = fmaf(zz, hC[u2][rg] - nn, nn);
        hC[u2][rg] = hv;
        lds[(q * 4 + rg) * 36 + u2 * 16 + c] = hv;
      }
    __builtin_amdgcn_wave_barrier();
    __builtin_amdgcn_s_waitcnt(0xC07F);  // lgkmcnt(0)
    f4 ha = *(const f4*)(lds + m * 36 + q * 8);
    f4 hb = *(const f4*)(lds + m * 36 + q * 8 + 4);
    __builtin_amdgcn_wave_barrier();
    if (store_msgs) {
      float* hp = hs + (size_t)pm[t] * H + q * 8;  // CSR-permuted row
      *(f4*)hp = ha;
      *(f4*)(hp + 4) = hb;
    }
    if (t + 1 < PLEN) {
      split8(ha, hb, hhi, hlo);
      xhi = xnhi; xlo = xnlo;
    } else if (!store_msgs) {
      // ---- fused readout MLP (last round): lane holds h[q*8..q*8+7] of path p0+m
      const float* RW = W + 12672;  // W1[256] b1[8] W2[64] b2[8] W3[8] b3[1]
      float part[8];
      #pragma unroll
      for (int i = 0; i < 8; ++i) {
        const f4* w4 = (const f4*)(RW + i * 32 + q * 8);
        f4 wa = w4[0], wb = w4[1];
        part[i] = wa[0] * ha[0] + wa[1] * ha[1] + wa[2] * ha[2] + wa[3] * ha[3]
                + wb[0] * hb[0] + wb[1] * hb[1] + wb[2] * hb[2] + wb[3] * hb[3];
      }
      #pragma unroll
      for (int i = 0; i < 8; ++i) {
        part[i] += __shfl_xor(part[i], 16);
        part[i] += __shfl_xor(part[i], 32);
      }
      if (q == 0) {
        float y1[8], y2[8];
        #pragma unroll
        for (int i = 0; i < 8; ++i) y1[i] = fmaxf(part[i] + RW[256 + i], 0.f);
        #pragma unroll
        for (int i = 0; i < 8; ++i) {
          float a = RW[328 + i];
          #pragma unroll
          for (int k = 0; k < 8; ++k) a = fmaf(RW[264 + i * 8 + k], y1[k], a);
          y2[i] = fmaxf(a, 0.f);
        }
        float o = RW[344];
        #pragma unroll
        for (int k = 0; k < 8; ++k) o = fmaf(RW[336 + k], y2[k], o);
        if (*flag) ((__hip_bfloat16*)out)[p0 + m] = __float2bfloat16(o);
        else       ((float*)out)[p0 + m] = o;
      }
    } else {
      float* pp = path_state + (size_t)(p0 + m) * H + q * 8;
      *(f4*)pp = ha;
      *(f4*)(pp + 4) = hb;
    }
  }
}

// ---------- fused aggregation + link GRU: 1 block = 16 links ----------
// hs is CSR-ordered: link l's messages occupy rows [offsets[l], offsets[l+1]).
__global__ __launch_bounds__(256) void agg_link_round(
    const int* __restrict__ offsets,
    const float* __restrict__ hs, float* __restrict__ link_state,
    unsigned short* __restrict__ lhi, unsigned short* __restrict__ llo,
    const float* __restrict__ W,
    const unsigned short* __restrict__ wih_hi, const unsigned short* __restrict__ wih_lo,
    const unsigned short* __restrict__ whh_hi, const unsigned short* __restrict__ whh_lo) {
  __shared__ float aggL[16 * 36];
  const int l0 = blockIdx.x * 16;
  const int wv = threadIdx.x >> 6;
  const int lane = threadIdx.x & 63;
  #pragma unroll 1
  for (int s = 0; s < 4; ++s) {
    const int li = wv * 4 + s;
    const int l = l0 + li;
    const int beg = offsets[l], end = offsets[l + 1];
    const f4* base4 = (const f4*)(hs + (size_t)beg * H);
    const int nvec = (end - beg) * (H / 4);
    f4 a0 = {0.f, 0.f, 0.f, 0.f}, a1 = {0.f, 0.f, 0.f, 0.f};
    int i = lane;
    for (; i + 64 < nvec; i += 128) {
      a0 += base4[i];
      a1 += base4[i + 64];
    }
    if (i < nvec) a0 += base4[i];
    a0 += a1;
    #pragma unroll
    for (int d = 32; d >= 8; d >>= 1) {
      #pragma unroll
      for (int k = 0; k < 4; ++k) a0[k] += __shfl_xor(a0[k], d);
    }
    if (lane < 8) *(f4*)(aggL + li * 36 + 4 * lane) = a0;
  }
  __syncthreads();
  if (threadIdx.x >= 64) return;
  // phase 2: wave 0 does a 16-link GRU step (full hi/lo weights)
  const int c = lane & 15, q = lane >> 4, m = c;
  bh8 wihH[6], wihL[6], whhH[6], whhL[6];
  #pragma unroll
  for (int tn = 0; tn < 6; ++tn) {
    size_t o = (size_t)(tn * 16 + c) * H + q * 8;
    wihH[tn] = *(const bh8*)(wih_hi + o);
    wihL[tn] = *(const bh8*)(wih_lo + o);
    whhH[tn] = *(const bh8*)(whh_hi + o);
    whhL[tn] = *(const bh8*)(whh_lo + o);
  }
  const float* bih = W + 6144;
  const float* bhh = W + 6240;
  float b_r[2], b_z[2], b_in[2], b_hn[2];
  #pragma unroll
  for (int u2 = 0; u2 < 2; ++u2) {
    int u = u2 * 16 + c;
    b_r[u2] = bih[u] + bhh[u];
    b_z[u2] = bih[32 + u] + bhh[32 + u];
    b_in[u2] = bih[64 + u];
    b_hn[u2] = bhh[64 + u];
  }
  float hC[2][4];
  #pragma unroll
  for (int u2 = 0; u2 < 2; ++u2)
    #pragma unroll
    for (int rg = 0; rg < 4; ++rg)
      hC[u2][rg] = link_state[(size_t)(l0 + q * 4 + rg) * H + u2 * 16 + c];
  f4 xa = *(const f4*)(aggL + m * 36 + q * 8);
  f4 xb = *(const f4*)(aggL + m * 36 + q * 8 + 4);
  f4 hfa = *(const f4*)(link_state + (size_t)(l0 + m) * H + q * 8);
  f4 hfb = *(const f4*)(link_state + (size_t)(l0 + m) * H + q * 8 + 4);
  bh8 xhi, xlo, hhi, hlo;
  split8(xa, xb, xhi, xlo);
  split8(hfa, hfb, hhi, hlo);
  const f4 z4 = {0.f, 0.f, 0.f, 0.f};
  f4 aR[2], aZ[2], aI[2], aHn[2];
  #pragma unroll
  for (int u2 = 0; u2 < 2; ++u2) {
    f4 a = z4;
    a = __builtin_amdgcn_mfma_f32_16x16x32_bf16(xhi, wihH[u2], a, 0, 0, 0);
    a = __builtin_amdgcn_mfma_f32_16x16x32_bf16(hhi, whhH[u2], a, 0, 0, 0);
    a = __builtin_amdgcn_mfma_f32_16x16x32_bf16(xlo, wihH[u2], a, 0, 0, 0);
    a = __builtin_amdgcn_mfma_f32_16x16x32_bf16(hlo, whhH[u2], a, 0, 0, 0);
    a = __builtin_amdgcn_mfma_f32_16x16x32_bf16(xhi, wihL[u2], a, 0, 0, 0);
    a = __builtin_amdgcn_mfma_f32_16x16x32_bf16(hhi, whhL[u2], a, 0, 0, 0);
    aR[u2] = a;
    f4 b = z4;
    b = __builtin_amdgcn_mfma_f32_16x16x32_bf16(xhi, wihH[2 + u2], b, 0, 0, 0);
    b = __builtin_amdgcn_mfma_f32_16x16x32_bf16(hhi, whhH[2 + u2], b, 0, 0, 0);
    b = __builtin_amdgcn_mfma_f32_16x16x32_bf16(xlo, wihH[2 + u2], b, 0, 0, 0);
    b = __builtin_amdgcn_mfma_f32_16x16x32_bf16(hlo, whhH[2 + u2], b, 0, 0, 0);
    b = __builtin_amdgcn_mfma_f32_16x16x32_bf16(xhi, wihL[2 + u2], b, 0, 0, 0);
    b = __builtin_amdgcn_mfma_f32_16x16x32_bf16(hhi, whhL[2 + u2], b, 0, 0, 0);
    aZ[u2] = b;
    f4 ci = z4;
    ci = __builtin_amdgcn_mfma_f32_16x16x32_bf16(xhi, wihH[4 + u2], ci, 0, 0, 0);
    ci = __builtin_amdgcn_mfma_f32_16x16x32_bf16(xlo, wihH[4 + u2], ci, 0, 0, 0);
    ci = __builtin_amdgcn_mfma_f32_16x16x32_bf16(xhi, wihL[4 + u2], ci, 0, 0, 0);
    aI[u2] = ci;
    f4 ch = z4;
    ch = __builtin_amdgcn_mfma_f32_16x16x32_bf16(hhi, whhH[4 + u2], ch, 0, 0, 0);
    ch = __builtin_amdgcn_mfma_f32_16x16x32_bf16(hlo, whhH[4 + u2], ch, 0, 0, 0);
    ch = __builtin_amdgcn_mfma_f32_16x16x32_bf16(hhi, whhL[4 + u2], ch, 0, 0, 0);
    aHn[u2] = ch;
  }
  #pragma unroll
  for (int u2 = 0; u2 < 2; ++u2)
    #pragma unroll
    for (int rg = 0; rg < 4; ++rg) {
      float rr = fast_sigm(aR[u2][rg] + b_r[u2]);
      float zz = fast_sigm(aZ[u2][rg] + b_z[u2]);
      float nn = fast_tanh2(fmaf(rr, aHn[u2][rg] + b_hn[u2], aI[u2][rg] + b_in[u2]));
      float hv = fmaf(zz, hC[u2][rg] - nn, nn);
      size_t idx = (size_t)(l0 + q * 4 + rg) * H + u2 * 16 + c;
      link_state[idx] = hv;
      unsigned u = __float_as_uint(hv);
      float fh = __uint_as_float(u & 0xffff0000u);
      lhi[idx] = (unsigned short)(u >> 16);
      llo[idx] = (unsigned short)(__float_as_uint(hv - fh) >> 16);
    }
}

// ---------- legacy fallback kernels (ws too small) ----------
__global__ __launch_bounds__(64) void path_round_atomic(
    const int* __restrict__ links, const float* __restrict__ link_state,
    float* __restrict__ path_state, float* __restrict__ agg,
    const float* __restrict__ W, int do_scatter) {
  int p = blockIdx.x * 64 + threadIdx.x;
  if (p >= NP) return;
  f2 h[16];
  const f2* ps2 = (const f2*)(path_state + (size_t)p * H);
  #pragma unroll
  for (int k = 0; k < 16; ++k) h[k] = ps2[k];
  int lk[PLEN];
  const int4* lp = (const int4*)(links + (size_t)p * PLEN);
  int4 la = lp[0], lb = lp[1];
  lk[0] = la.x; lk[1] = la.y; lk[2] = la.z; lk[3] = la.w;
  lk[4] = lb.x; lk[5] = lb.y; lk[6] = lb.z; lk[7] = lb.w;
  #pragma unroll 1
  for (int t = 0; t < PLEN; ++t) {
    const f2* xs = (const f2*)(link_state + (size_t)lk[t] * H);
    f2 x[16];
    #pragma unroll
    for (int k = 0; k < 16; ++k) x[k] = xs[k];
    gru_cell_f2(W, x, h);
    if (do_scatter) {
      float* dst = agg + (size_t)lk[t] * H;
      #pragma unroll
      for (int k = 0; k < 16; ++k) {
        unsafeAtomicAdd(dst + 2 * k, h[k].x);
        unsafeAtomicAdd(dst + 2 * k + 1, h[k].y);
      }
    }
  }
  f2* po = (f2*)(path_state + (size_t)p * H);
  #pragma unroll
  for (int k = 0; k < 16; ++k) po[k] = h[k];
}

__global__ __launch_bounds__(64) void link_round_scalar(
    const float* __restrict__ agg, float* __restrict__ link_state,
    const float* __restrict__ W) {
  int li = blockIdx.x * 64 + threadIdx.x;
  if (li >= NL) return;
  f2 x[16], h[16];
  const f2* xa = (const f2*)(agg + (size_t)li * H);
  f2* hsrow = (f2*)(link_state + (size_t)li * H);
  #pragma unroll
  for (int k = 0; k < 16; ++k) { x[k] = xa[k]; h[k] = hsrow[k]; }
  gru_cell_f2(W, x, h);
  #pragma unroll
  for (int k = 0; k < 16; ++k) hsrow[k] = h[k];
}

__global__ __launch_bounds__(256) void readout_kernel(
    const float* __restrict__ path_state, const float* __restrict__ W,
    const int* __restrict__ flag, void* __restrict__ out) {
  int p = blockIdx.x * 256 + threadIdx.x;
  if (p >= NP) return;
  const float* W1 = W;
  const float* b1 = W + 256;
  const float* W2 = W + 264;
  const float* b2 = W + 328;
  const float* W3 = W + 336;
  const float* b3 = W + 344;
  float xv[32];
  const float4* xp = (const float4*)(path_state + (size_t)p * H);
  #pragma unroll
  for (int k = 0; k < 8; ++k) {
    float4 v = xp[k];
    xv[4 * k] = v.x; xv[4 * k + 1] = v.y; xv[4 * k + 2] = v.z; xv[4 * k + 3] = v.w;
  }
  float y1[8];
  #pragma unroll
  for (int i = 0; i < 8; ++i) {
    float a = b1[i];
    #pragma unroll
    for (int k = 0; k < 32; ++k) a = fmaf(W1[i * 32 + k], xv[k], a);
    y1[i] = fmaxf(a, 0.f);
  }
  float y2[8];
  #pragma unroll
  for (int i = 0; i < 8; ++i) {
    float a = b2[i];
    #pragma unroll
    for (int k = 0; k < 8; ++k) a = fmaf(W2[i * 8 + k], y1[k], a);
    y2[i] = fmaxf(a, 0.f);
  }
  float o = b3[0];
  #pragma unroll
  for (int k = 0; k < 8; ++k) o = fmaf(W3[k], y2[k], o);
  if (*flag) ((__hip_bfloat16*)out)[p] = __float2bfloat16(o);
  else       ((float*)out)[p] = o;
}

extern "C" void kernel_launch(void* const* d_in, const int* in_sizes, int n_in,
                              void* d_out, int out_size, void* d_ws, size_t ws_size,
                              hipStream_t stream) {
  (void)in_sizes; (void)n_in; (void)out_size;
  const int* links = (const int*)d_in[0];
  const void* cap = d_in[3];
  const void* bw  = d_in[4];

  float* ws = (float*)d_ws;
  float* link_state = ws + LINK_OFF;
  float* path_state = ws + PATH_OFF;
  float* agg        = ws + AGG_OFF;   // fallback only
  unsigned short* lhi = (unsigned short*)(ws + AGG_OFF);            // gather mode
  unsigned short* llo = (unsigned short*)(ws + AGG_OFF + 160000);   // gather mode
  float* wts        = ws + WTS_OFF;
  int*   flag       = (int*)(ws + FLAG_OFF);
  int*   ibase      = (int*)(ws + INT_OFF);
  int*   counts     = ibase;
  int*   offsets    = ibase + 10000;
  int*   cursor     = ibase + 20016;
  int*   perm       = ibase + 30016;
  float* hs         = ws + HS_OFF;

  WPack wp;
  for (int i = 0; i < 8; ++i)
    wp.p[i] = (unsigned short*)(ws + PW_OFF + i * 1600);

  const bool use_gather = ws_size >= WS_NEED_FLOATS * sizeof(float);

  probe_dtype<<<1, 64, 0, stream>>>((const unsigned int*)cap, flag);

  BfSegs segs;
  const int srcidx[14] = {5, 6, 7, 8, 9, 10, 11, 12, 13, 14, 15, 16, 17, 18};
  const int offs[14]   = {0, 3072, 6144, 6240, 6336, 9408, 12480, 12576,
                          12672, 12928, 12936, 13000, 13008, 13016};
  const int lens[14]   = {3072, 3072, 96, 96, 3072, 3072, 96, 96,
                          256, 8, 64, 8, 8, 1};
  for (int i = 0; i < 14; ++i) {
    segs.s[i].src = d_in[srcidx[i]];
    segs.s[i].dstoff = offs[i];
    segs.s[i].len = lens[i];
  }
  convert_weights<<<14, 256, 0, stream>>>(segs, wp, flag, wts);
  init_states<<<(NP * H + 255) / 256, 256, 0, stream>>>(
      cap, bw, flag, link_state, lhi, llo, path_state);

  if (use_gather) {
    hipMemsetAsync(counts, 0, NL * sizeof(int), stream);
    csr_count<<<(E_TOT + 255) / 256, 256, 0, stream>>>(links, counts);
    csr_scan<<<1, 256, 0, stream>>>(counts, offsets, cursor);
    csr_fill<<<(E_TOT + 255) / 256, 256, 0, stream>>>(links, cursor, perm);

    const int path_blocks = (NP / 16 + 3) / 4;  // 1563
    for (int r = 0; r < NROUNDS; ++r) {
      const int last = (r == NROUNDS - 1);
      path_round_mfma<<<path_blocks, 256, 0, stream>>>(
          links, perm, lhi, llo, path_state, hs, wts,
          wp.p[0], wp.p[1], wp.p[2], wp.p[3], flag, d_out, !last);
      if (!last) {
        agg_link_round<<<NL / 16, 256, 0, stream>>>(
            offsets, hs, link_state, lhi, llo,
            wts + 6336, wp.p[4], wp.p[5], wp.p[6], wp.p[7]);
      }
    }
  } else {
    for (int r = 0; r < NROUNDS; ++r) {
      const int last = (r == NROUNDS - 1);
      if (!last) hipMemsetAsync(agg, 0, NL * H * sizeof(float), stream);
      path_round_atomic<<<(NP + 63) / 64, 64, 0, stream>>>(
          links, link_state, path_state, agg, wts, !last);
      if (!last)
        link_round_scalar<<<(NL + 63) / 64, 64, 0, stream>>>(agg, link_state, wts + 6336);
    }
    readout_kernel<<<(NP + 255) / 256, 256, 0, stream>>>(
        path_state, wts + 12672, flag, d_out);
  }
}

// Round 12
// 929.268 us; speedup vs baseline: 2.4714x; 2.4714x over previous
//
#include <hip/hip_runtime.h>
#include <hip/hip_bf16.h>

#define NL 10000
#define NP 100000
#define PLEN 8
#define H 32
#define NROUNDS 8
#define E_TOT (NP * PLEN)

typedef float f2 __attribute__((ext_vector_type(2)));
typedef float f4 __attribute__((ext_vector_type(4)));
typedef short bh8 __attribute__((ext_vector_type(8)));

// ---------- ws layout (float offsets) ----------
#define LINK_OFF   0          // 320000 fp32 link_state
#define PATH_OFF   320000     // 3200000
#define AGG_OFF    3520000    // 320000: gather mode reuses as LHI(160000)+LLO(160000)
#define WTS_OFF    3840000    // 13345 fp32 weights
#define PW_OFF     3853400    // 8 regions x 1600 floats (ushort[3072] each)
#define FLAG_OFF   3869000
#define INT_OFF    3870000    // ints: counts | offsets@10000 | cursor@20016 | perm@30016 (800000)
#define HS_OFF     4700032
#define WS_NEED_FLOATS (HS_OFF + (size_t)E_TOT * H)

#define LOG2E 1.44269504f

__device__ __forceinline__ float bf2f(unsigned short u) {
  union { unsigned int i; float f; } v; v.i = ((unsigned int)u) << 16; return v.f;
}
__device__ __forceinline__ float fast_exp2(float x) {
#if __has_builtin(__builtin_amdgcn_exp2f)
  return __builtin_amdgcn_exp2f(x);
#else
  return __expf(x * 0.69314718f);
#endif
}
__device__ __forceinline__ float fast_rcp(float x) {
#if __has_builtin(__builtin_amdgcn_rcpf)
  return __builtin_amdgcn_rcpf(x);
#else
  return 1.f / x;
#endif
}
__device__ __forceinline__ float fast_sigm(float x) {
  return fast_rcp(1.f + fast_exp2(-LOG2E * x));
}
__device__ __forceinline__ float fast_tanh2(float x) {
  return 1.f - 2.f * fast_rcp(1.f + fast_exp2((2.f * LOG2E) * x));
}
__device__ __forceinline__ float loadf(const void* p, long i, bool bf) {
  return bf ? bf2f(((const unsigned short*)p)[i]) : ((const float*)p)[i];
}

// split 8 fp32 into bf16 hi + bf16 lo (residual), trunc rounding
__device__ __forceinline__ void split8(f4 a, f4 b, bh8& hi, bh8& lo) {
  #pragma unroll
  for (int i = 0; i < 4; ++i) {
    unsigned ua = __float_as_uint(a[i]);
    float hfa = __uint_as_float(ua & 0xffff0000u);
    hi[i] = (short)(ua >> 16);
    lo[i] = (short)(__float_as_uint(a[i] - hfa) >> 16);
    unsigned ub = __float_as_uint(b[i]);
    float hfb = __uint_as_float(ub & 0xffff0000u);
    hi[4 + i] = (short)(ub >> 16);
    lo[4 + i] = (short)(__float_as_uint(b[i] - hfb) >> 16);
  }
}

// ---------- dtype probe ----------
__global__ void probe_dtype(const unsigned int* __restrict__ cap_words,
                            int* __restrict__ flag) {
  int lane = threadIdx.x;
  int c = 0;
  #pragma unroll
  for (int i = 0; i < 4; ++i) {
    unsigned int b = (cap_words[lane * 4 + i] >> 8) & 0xFF;
    if (b >= 0x30 && b < 0x40) ++c;
  }
  #pragma unroll
  for (int d = 32; d > 0; d >>= 1) c += __shfl_down(c, d);
  if (lane == 0) *flag = (c > 128) ? 1 : 0;
}

// ---------- scalar GRU cell (fallback path only) ----------
__device__ __forceinline__ void gru_cell_f2(const float* __restrict__ W,
                                            const f2 x[16], f2 h[16]) {
  const f2* Wih = (const f2*)W;
  const f2* Whh = (const f2*)(W + 3072);
  const float* bih = W + 6144;
  const float* bhh = W + 6240;
  f2 hn[16];
  #pragma unroll
  for (int jj = 0; jj < 16; ++jj) {
    #pragma unroll
    for (int s = 0; s < 2; ++s) {
      const int j = 2 * jj + s;
      f2 ar = {0.f, 0.f}, az = {0.f, 0.f}, an = {0.f, 0.f}, ah = {0.f, 0.f};
      #pragma unroll
      for (int k = 0; k < 16; ++k) {
        ar = __builtin_elementwise_fma(Wih[j * 16 + k], x[k], ar);
        ar = __builtin_elementwise_fma(Whh[j * 16 + k], h[k], ar);
        az = __builtin_elementwise_fma(Wih[(H + j) * 16 + k], x[k], az);
        az = __builtin_elementwise_fma(Whh[(H + j) * 16 + k], h[k], az);
        an = __builtin_elementwise_fma(Wih[(2 * H + j) * 16 + k], x[k], an);
        ah = __builtin_elementwise_fma(Whh[(2 * H + j) * 16 + k], h[k], ah);
      }
      float r = fast_sigm(ar.x + ar.y + bih[j] + bhh[j]);
      float z = fast_sigm(az.x + az.y + bih[H + j] + bhh[H + j]);
      float n = fast_tanh2(an.x + an.y + bih[2 * H + j] +
                           r * (ah.x + ah.y + bhh[2 * H + j]));
      float hold = (s == 0) ? h[jj].x : h[jj].y;
      float hv = n + z * (hold - n);
      if (s == 0) hn[jj].x = hv; else hn[jj].y = hv;
    }
  }
  #pragma unroll
  for (int k = 0; k < 16; ++k) h[k] = hn[k];
}

// ---------- weight conversion (+ hi/lo bf16 splits of all 4 GRU matrices) ----------
struct BfSeg { const void* src; int dstoff; int len; };
struct BfSegs { BfSeg s[14]; };
struct WPack { unsigned short* p[8]; };

__global__ void convert_weights(BfSegs segs, WPack wp, const int* __restrict__ flag,
                                float* __restrict__ dst) {
  const bool bf = (*flag != 0);
  const int si = blockIdx.x;
  const void* p = segs.s[si].src;
  const int off = segs.s[si].dstoff, len = segs.s[si].len;
  int hix = -1;
  if (si == 0) hix = 0; else if (si == 1) hix = 2;
  else if (si == 4) hix = 4; else if (si == 5) hix = 6;
  for (int i = threadIdx.x; i < len; i += blockDim.x) {
    float f = loadf(p, i, bf);
    dst[off + i] = f;
    if (hix >= 0) {
      unsigned u = __float_as_uint(f);
      float fh = __uint_as_float(u & 0xffff0000u);
      wp.p[hix][i] = (unsigned short)(u >> 16);
      wp.p[hix + 1][i] = (unsigned short)(__float_as_uint(f - fh) >> 16);
    }
  }
}

__global__ void init_states(const void* __restrict__ cap,
                            const void* __restrict__ bw,
                            const int* __restrict__ flag,
                            float* __restrict__ link_state,
                            unsigned short* __restrict__ lhi,
                            unsigned short* __restrict__ llo,
                            float* __restrict__ path_state) {
  const bool bf = (*flag != 0);
  int i = blockIdx.x * blockDim.x + threadIdx.x;
  if (i < NP * H) path_state[i] = ((i & (H - 1)) == 0) ? loadf(bw, i >> 5, bf) : 0.f;
  if (i < NL * H) {
    float v = ((i & (H - 1)) == 0) ? loadf(cap, i >> 5, bf) : 0.f;
    link_state[i] = v;
    unsigned u = __float_as_uint(v);
    float fh = __uint_as_float(u & 0xffff0000u);
    lhi[i] = (unsigned short)(u >> 16);
    llo[i] = (unsigned short)(__float_as_uint(v - fh) >> 16);
  }
}

// ---------- CSR build ----------
__global__ void csr_count(const int* __restrict__ links, int* __restrict__ counts) {
  int e = blockIdx.x * blockDim.x + threadIdx.x;
  if (e < E_TOT) atomicAdd(&counts[links[e]], 1);
}

__global__ __launch_bounds__(256) void csr_scan(const int* __restrict__ counts,
                                                int* __restrict__ offsets,
                                                int* __restrict__ cursor) {
  __shared__ int part[256];
  const int t = threadIdx.x;
  const int base = t * 40;
  int s = 0;
  for (int i = 0; i < 40; ++i) {
    int idx = base + i;
    if (idx < NL) s += counts[idx];
  }
  part[t] = s;
  __syncthreads();
  for (int d = 1; d < 256; d <<= 1) {
    int v = (t >= d) ? part[t - d] : 0;
    __syncthreads();
    part[t] += v;
    __syncthreads();
  }
  int run = (t > 0) ? part[t - 1] : 0;
  for (int i = 0; i < 40; ++i) {
    int idx = base + i;
    if (idx < NL) {
      offsets[idx] = run;
      cursor[idx] = run;
      run += counts[idx];
    }
  }
  if (t == 255) offsets[NL] = run;
}

// perm[e] = CSR slot of edge e — path kernel scatters messages into CSR order
__global__ void csr_fill(const int* __restrict__ links, int* __restrict__ cursor,
                         int* __restrict__ perm) {
  int e = blockIdx.x * blockDim.x + threadIdx.x;
  if (e < E_TOT) {
    int l = links[e];
    int pos = atomicAdd(&cursor[l], 1);
    perm[e] = pos;
  }
}

// ---------- MFMA path round: block=256 = 4 waves, each wave = 16 paths ----------
// fp32-exact via hi/lo splits of BOTH weights and states (lo*lo dropped ~2^-17).
// Last round (store_msgs==0): fused readout MLP, no path_state write, no hs write.
// NOTE: no min-waves launch bound — forcing 5 waves/EU clamped VGPR to 48 and
// spilled everything (FETCH 18->593 MB, 3x slower). Compiler picks ~104 VGPRs.
__global__ __launch_bounds__(256) void path_round_mfma(
    const int* __restrict__ links, const int* __restrict__ perm,
    const unsigned short* __restrict__ lhi, const unsigned short* __restrict__ llo,
    float* __restrict__ path_state, float* __restrict__ hs,
    const float* __restrict__ W,
    const unsigned short* __restrict__ wih_hi, const unsigned short* __restrict__ wih_lo,
    const unsigned short* __restrict__ whh_hi, const unsigned short* __restrict__ whh_lo,
    const int* __restrict__ flag, void* __restrict__ out,
    int store_msgs) {
  __shared__ float lds_all[4 * 16 * 36];
  const int wv = threadIdx.x >> 6;
  const int tile = blockIdx.x * 4 + wv;
  if (tile >= NP / 16) return;
  const int p0 = tile * 16;
  const int lane = threadIdx.x & 63;
  const int c = lane & 15, q = lane >> 4, m = c;
  float* lds = lds_all + wv * (16 * 36);

  bh8 wihH[6], wihL[6], whhH[6], whhL[6];
  #pragma unroll
  for (int tn = 0; tn < 6; ++tn) {
    size_t o = (size_t)(tn * 16 + c) * H + q * 8;
    wihH[tn] = *(const bh8*)(wih_hi + o);
    wihL[tn] = *(const bh8*)(wih_lo + o);
    whhH[tn] = *(const bh8*)(whh_hi + o);
    whhL[tn] = *(const bh8*)(whh_lo + o);
  }
  const float* bih = W + 6144;
  const float* bhh = W + 6240;
  float b_r[2], b_z[2], b_in[2], b_hn[2];
  #pragma unroll
  for (int u2 = 0; u2 < 2; ++u2) {
    int u = u2 * 16 + c;
    b_r[u2] = bih[u] + bhh[u];
    b_z[u2] = bih[32 + u] + bhh[32 + u];
    b_in[u2] = bih[64 + u];
    b_hn[u2] = bhh[64 + u];
  }
  float hC[2][4];
  #pragma unroll
  for (int u2 = 0; u2 < 2; ++u2)
    #pragma unroll
    for (int rg = 0; rg < 4; ++rg)
      hC[u2][rg] = path_state[(size_t)(p0 + q * 4 + rg) * H + u2 * 16 + c];
  f4 hfa = *(const f4*)(path_state + (size_t)(p0 + m) * H + q * 8);
  f4 hfb = *(const f4*)(path_state + (size_t)(p0 + m) * H + q * 8 + 4);
  bh8 hhi, hlo;
  split8(hfa, hfb, hhi, hlo);
  int lk[PLEN], pm[PLEN];
  {
    const int4* lp = (const int4*)(links + (size_t)(p0 + m) * PLEN);
    int4 a = lp[0], b = lp[1];
    lk[0] = a.x; lk[1] = a.y; lk[2] = a.z; lk[3] = a.w;
    lk[4] = b.x; lk[5] = b.y; lk[6] = b.z; lk[7] = b.w;
    const int4* qp = (const int4*)(perm + (size_t)(p0 + m) * PLEN);
    int4 e = qp[0], f = qp[1];
    pm[0] = e.x; pm[1] = e.y; pm[2] = e.z; pm[3] = e.w;
    pm[4] = f.x; pm[5] = f.y; pm[6] = f.z; pm[7] = f.w;
  }
  bh8 xhi = *(const bh8*)(lhi + (size_t)lk[0] * H + q * 8);
  bh8 xlo = *(const bh8*)(llo + (size_t)lk[0] * H + q * 8);
  const f4 z4 = {0.f, 0.f, 0.f, 0.f};

  #pragma unroll 1
  for (int t = 0; t < PLEN; ++t) {
    bh8 xnhi, xnlo;
    if (t + 1 < PLEN) {
      xnhi = *(const bh8*)(lhi + (size_t)lk[t + 1] * H + q * 8);
      xnlo = *(const bh8*)(llo + (size_t)lk[t + 1] * H + q * 8);
    }
    f4 aR[2], aZ[2], aI[2], aHn[2];
    #pragma unroll
    for (int u2 = 0; u2 < 2; ++u2) {
      f4 a = z4;
      a = __builtin_amdgcn_mfma_f32_16x16x32_bf16(xhi, wihH[u2], a, 0, 0, 0);
      a = __builtin_amdgcn_mfma_f32_16x16x32_bf16(hhi, whhH[u2], a, 0, 0, 0);
      a = __builtin_amdgcn_mfma_f32_16x16x32_bf16(xlo, wihH[u2], a, 0, 0, 0);
      a = __builtin_amdgcn_mfma_f32_16x16x32_bf16(hlo, whhH[u2], a, 0, 0, 0);
      a = __builtin_amdgcn_mfma_f32_16x16x32_bf16(xhi, wihL[u2], a, 0, 0, 0);
      a = __builtin_amdgcn_mfma_f32_16x16x32_bf16(hhi, whhL[u2], a, 0, 0, 0);
      aR[u2] = a;
      f4 b = z4;
      b = __builtin_amdgcn_mfma_f32_16x16x32_bf16(xhi, wihH[2 + u2], b, 0, 0, 0);
      b = __builtin_amdgcn_mfma_f32_16x16x32_bf16(hhi, whhH[2 + u2], b, 0, 0, 0);
      b = __builtin_amdgcn_mfma_f32_16x16x32_bf16(xlo, wihH[2 + u2], b, 0, 0, 0);
      b = __builtin_amdgcn_mfma_f32_16x16x32_bf16(hlo, whhH[2 + u2], b, 0, 0, 0);
      b = __builtin_amdgcn_mfma_f32_16x16x32_bf16(xhi, wihL[2 + u2], b, 0, 0, 0);
      b = __builtin_amdgcn_mfma_f32_16x16x32_bf16(hhi, whhL[2 + u2], b, 0, 0, 0);
      aZ[u2] = b;
      f4 ci = z4;
      ci = __builtin_amdgcn_mfma_f32_16x16x32_bf16(xhi, wihH[4 + u2], ci, 0, 0, 0);
      ci = __builtin_amdgcn_mfma_f32_16x16x32_bf16(xlo, wihH[4 + u2], ci, 0, 0, 0);
      ci = __builtin_amdgcn_mfma_f32_16x16x32_bf16(xhi, wihL[4 + u2], ci, 0, 0, 0);
      aI[u2] = ci;
      f4 ch = z4;
      ch = __builtin_amdgcn_mfma_f32_16x16x32_bf16(hhi, whhH[4 + u2], ch, 0, 0, 0);
      ch = __builtin_amdgcn_mfma_f32_16x16x32_bf16(hlo, whhH[4 + u2], ch, 0, 0, 0);
      ch = __builtin_amdgcn_mfma_f32_16x16x32_bf16(hhi, whhL[4 + u2], ch, 0, 0, 0);
      aHn[u2] = ch;
    }
    #pragma unroll
    for (int u2 = 0; u2 < 2; ++u2)
      #pragma unroll
      for (int rg = 0; rg < 4; ++rg) {
        float rr = fast_sigm(aR[u2][rg] + b_r[u2]);
        float zz = fast_sigm(aZ[u2][rg] + b_z[u2]);
        float nn = fast_tanh2(fmaf(rr, aHn[u2][rg] + b_hn[u2], aI[u2][rg] + b_in[u2]));
        float hv = fmaf(zz, hC[u2][rg] - nn, nn);
        hC[u2][rg] = hv;
        lds[(q * 4 + rg) * 36 + u2 * 16 + c] = hv;
      }
    __builtin_amdgcn_wave_barrier();
    __builtin_amdgcn_s_waitcnt(0xC07F);  // lgkmcnt(0)
    f4 ha = *(const f4*)(lds + m * 36 + q * 8);
    f4 hb = *(const f4*)(lds + m * 36 + q * 8 + 4);
    __builtin_amdgcn_wave_barrier();
    if (store_msgs) {
      float* hp = hs + (size_t)pm[t] * H + q * 8;  // CSR-permuted row
      *(f4*)hp = ha;
      *(f4*)(hp + 4) = hb;
    }
    if (t + 1 < PLEN) {
      split8(ha, hb, hhi, hlo);
      xhi = xnhi; xlo = xnlo;
    } else if (!store_msgs) {
      // ---- fused readout MLP (last round): lane holds h[q*8..q*8+7] of path p0+m
      const float* RW = W + 12672;  // W1[256] b1[8] W2[64] b2[8] W3[8] b3[1]
      float part[8];
      #pragma unroll
      for (int i = 0; i < 8; ++i) {
        const f4* w4 = (const f4*)(RW + i * 32 + q * 8);
        f4 wa = w4[0], wb = w4[1];
        part[i] = wa[0] * ha[0] + wa[1] * ha[1] + wa[2] * ha[2] + wa[3] * ha[3]
                + wb[0] * hb[0] + wb[1] * hb[1] + wb[2] * hb[2] + wb[3] * hb[3];
      }
      #pragma unroll
      for (int i = 0; i < 8; ++i) {
        part[i] += __shfl_xor(part[i], 16);
        part[i] += __shfl_xor(part[i], 32);
      }
      if (q == 0) {
        float y1[8], y2[8];
        #pragma unroll
        for (int i = 0; i < 8; ++i) y1[i] = fmaxf(part[i] + RW[256 + i], 0.f);
        #pragma unroll
        for (int i = 0; i < 8; ++i) {
          float a = RW[328 + i];
          #pragma unroll
          for (int k = 0; k < 8; ++k) a = fmaf(RW[264 + i * 8 + k], y1[k], a);
          y2[i] = fmaxf(a, 0.f);
        }
        float o = RW[344];
        #pragma unroll
        for (int k = 0; k < 8; ++k) o = fmaf(RW[336 + k], y2[k], o);
        if (*flag) ((__hip_bfloat16*)out)[p0 + m] = __float2bfloat16(o);
        else       ((float*)out)[p0 + m] = o;
      }
    } else {
      float* pp = path_state + (size_t)(p0 + m) * H + q * 8;
      *(f4*)pp = ha;
      *(f4*)(pp + 4) = hb;
    }
  }
}

// ---------- fused aggregation + link GRU: 1 block = 16 links ----------
// hs is CSR-ordered: link l's messages occupy rows [offsets[l], offsets[l+1]).
__global__ __launch_bounds__(256) void agg_link_round(
    const int* __restrict__ offsets,
    const float* __restrict__ hs, float* __restrict__ link_state,
    unsigned short* __restrict__ lhi, unsigned short* __restrict__ llo,
    const float* __restrict__ W,
    const unsigned short* __restrict__ wih_hi, const unsigned short* __restrict__ wih_lo,
    const unsigned short* __restrict__ whh_hi, const unsigned short* __restrict__ whh_lo) {
  __shared__ float aggL[16 * 36];
  const int l0 = blockIdx.x * 16;
  const int wv = threadIdx.x >> 6;
  const int lane = threadIdx.x & 63;
  #pragma unroll 1
  for (int s = 0; s < 4; ++s) {
    const int li = wv * 4 + s;
    const int l = l0 + li;
    const int beg = offsets[l], end = offsets[l + 1];
    const f4* base4 = (const f4*)(hs + (size_t)beg * H);
    const int nvec = (end - beg) * (H / 4);
    f4 a0 = {0.f, 0.f, 0.f, 0.f}, a1 = {0.f, 0.f, 0.f, 0.f};
    int i = lane;
    for (; i + 64 < nvec; i += 128) {
      a0 += base4[i];
      a1 += base4[i + 64];
    }
    if (i < nvec) a0 += base4[i];
    a0 += a1;
    #pragma unroll
    for (int d = 32; d >= 8; d >>= 1) {
      #pragma unroll
      for (int k = 0; k < 4; ++k) a0[k] += __shfl_xor(a0[k], d);
    }
    if (lane < 8) *(f4*)(aggL + li * 36 + 4 * lane) = a0;
  }
  __syncthreads();
  if (threadIdx.x >= 64) return;
  // phase 2: wave 0 does a 16-link GRU step (full hi/lo weights)
  const int c = lane & 15, q = lane >> 4, m = c;
  bh8 wihH[6], wihL[6], whhH[6], whhL[6];
  #pragma unroll
  for (int tn = 0; tn < 6; ++tn) {
    size_t o = (size_t)(tn * 16 + c) * H + q * 8;
    wihH[tn] = *(const bh8*)(wih_hi + o);
    wihL[tn] = *(const bh8*)(wih_lo + o);
    whhH[tn] = *(const bh8*)(whh_hi + o);
    whhL[tn] = *(const bh8*)(whh_lo + o);
  }
  const float* bih = W + 6144;
  const float* bhh = W + 6240;
  float b_r[2], b_z[2], b_in[2], b_hn[2];
  #pragma unroll
  for (int u2 = 0; u2 < 2; ++u2) {
    int u = u2 * 16 + c;
    b_r[u2] = bih[u] + bhh[u];
    b_z[u2] = bih[32 + u] + bhh[32 + u];
    b_in[u2] = bih[64 + u];
    b_hn[u2] = bhh[64 + u];
  }
  float hC[2][4];
  #pragma unroll
  for (int u2 = 0; u2 < 2; ++u2)
    #pragma unroll
    for (int rg = 0; rg < 4; ++rg)
      hC[u2][rg] = link_state[(size_t)(l0 + q * 4 + rg) * H + u2 * 16 + c];
  f4 xa = *(const f4*)(aggL + m * 36 + q * 8);
  f4 xb = *(const f4*)(aggL + m * 36 + q * 8 + 4);
  f4 hfa = *(const f4*)(link_state + (size_t)(l0 + m) * H + q * 8);
  f4 hfb = *(const f4*)(link_state + (size_t)(l0 + m) * H + q * 8 + 4);
  bh8 xhi, xlo, hhi, hlo;
  split8(xa, xb, xhi, xlo);
  split8(hfa, hfb, hhi, hlo);
  const f4 z4 = {0.f, 0.f, 0.f, 0.f};
  f4 aR[2], aZ[2], aI[2], aHn[2];
  #pragma unroll
  for (int u2 = 0; u2 < 2; ++u2) {
    f4 a = z4;
    a = __builtin_amdgcn_mfma_f32_16x16x32_bf16(xhi, wihH[u2], a, 0, 0, 0);
    a = __builtin_amdgcn_mfma_f32_16x16x32_bf16(hhi, whhH[u2], a, 0, 0, 0);
    a = __builtin_amdgcn_mfma_f32_16x16x32_bf16(xlo, wihH[u2], a, 0, 0, 0);
    a = __builtin_amdgcn_mfma_f32_16x16x32_bf16(hlo, whhH[u2], a, 0, 0, 0);
    a = __builtin_amdgcn_mfma_f32_16x16x32_bf16(xhi, wihL[u2], a, 0, 0, 0);
    a = __builtin_amdgcn_mfma_f32_16x16x32_bf16(hhi, whhL[u2], a, 0, 0, 0);
    aR[u2] = a;
    f4 b = z4;
    b = __builtin_amdgcn_mfma_f32_16x16x32_bf16(xhi, wihH[2 + u2], b, 0, 0, 0);
    b = __builtin_amdgcn_mfma_f32_16x16x32_bf16(hhi, whhH[2 + u2], b, 0, 0, 0);
    b = __builtin_amdgcn_mfma_f32_16x16x32_bf16(xlo, wihH[2 + u2], b, 0, 0, 0);
    b = __builtin_amdgcn_mfma_f32_16x16x32_bf16(hlo, whhH[2 + u2], b, 0, 0, 0);
    b = __builtin_amdgcn_mfma_f32_16x16x32_bf16(xhi, wihL[2 + u2], b, 0, 0, 0);
    b = __builtin_amdgcn_mfma_f32_16x16x32_bf16(hhi, whhL[2 + u2], b, 0, 0, 0);
    aZ[u2] = b;
    f4 ci = z4;
    ci = __builtin_amdgcn_mfma_f32_16x16x32_bf16(xhi, wihH[4 + u2], ci, 0, 0, 0);
    ci = __builtin_amdgcn_mfma_f32_16x16x32_bf16(xlo, wihH[4 + u2], ci, 0, 0, 0);
    ci = __builtin_amdgcn_mfma_f32_16x16x32_bf16(xhi, wihL[4 + u2], ci, 0, 0, 0);
    aI[u2] = ci;
    f4 ch = z4;
    ch = __builtin_amdgcn_mfma_f32_16x16x32_bf16(hhi, whhH[4 + u2], ch, 0, 0, 0);
    ch = __builtin_amdgcn_mfma_f32_16x16x32_bf16(hlo, whhH[4 + u2], ch, 0, 0, 0);
    ch = __builtin_amdgcn_mfma_f32_16x16x32_bf16(hhi, whhL[4 + u2], ch, 0, 0, 0);
    aHn[u2] = ch;
  }
  #pragma unroll
  for (int u2 = 0; u2 < 2; ++u2)
    #pragma unroll
    for (int rg = 0; rg < 4; ++rg) {
      float rr = fast_sigm(aR[u2][rg] + b_r[u2]);
      float zz = fast_sigm(aZ[u2][rg] + b_z[u2]);
      float nn = fast_tanh2(fmaf(rr, aHn[u2][rg] + b_hn[u2], aI[u2][rg] + b_in[u2]));
      float hv = fmaf(zz, hC[u2][rg] - nn, nn);
      size_t idx = (size_t)(l0 + q * 4 + rg) * H + u2 * 16 + c;
      link_state[idx] = hv;
      unsigned u = __float_as_uint(hv);
      float fh = __uint_as_float(u & 0xffff0000u);
      lhi[idx] = (unsigned short)(u >> 16);
      llo[idx] = (unsigned short)(__float_as_uint(hv - fh) >> 16);
    }
}

// ---------- legacy fallback kernels (ws too small) ----------
__global__ __launch_bounds__(64) void path_round_atomic(
    const int* __restrict__ links, const float* __restrict__ link_state,
    float* __restrict__ path_state, float* __restrict__ agg,
    const float* __restrict__ W, int do_scatter) {
  int p = blockIdx.x * 64 + threadIdx.x;
  if (p >= NP) return;
  f2 h[16];
  const f2* ps2 = (const f2*)(path_state + (size_t)p * H);
  #pragma unroll
  for (int k = 0; k < 16; ++k) h[k] = ps2[k];
  int lk[PLEN];
  const int4* lp = (const int4*)(links + (size_t)p * PLEN);
  int4 la = lp[0], lb = lp[1];
  lk[0] = la.x; lk[1] = la.y; lk[2] = la.z; lk[3] = la.w;
  lk[4] = lb.x; lk[5] = lb.y; lk[6] = lb.z; lk[7] = lb.w;
  #pragma unroll 1
  for (int t = 0; t < PLEN; ++t) {
    const f2* xs = (const f2*)(link_state + (size_t)lk[t] * H);
    f2 x[16];
    #pragma unroll
    for (int k = 0; k < 16; ++k) x[k] = xs[k];
    gru_cell_f2(W, x, h);
    if (do_scatter) {
      float* dst = agg + (size_t)lk[t] * H;
      #pragma unroll
      for (int k = 0; k < 16; ++k) {
        unsafeAtomicAdd(dst + 2 * k, h[k].x);
        unsafeAtomicAdd(dst + 2 * k + 1, h[k].y);
      }
    }
  }
  f2* po = (f2*)(path_state + (size_t)p * H);
  #pragma unroll
  for (int k = 0; k < 16; ++k) po[k] = h[k];
}

__global__ __launch_bounds__(64) void link_round_scalar(
    const float* __restrict__ agg, float* __restrict__ link_state,
    const float* __restrict__ W) {
  int li = blockIdx.x * 64 + threadIdx.x;
  if (li >= NL) return;
  f2 x[16], h[16];
  const f2* xa = (const f2*)(agg + (size_t)li * H);
  f2* hsrow = (f2*)(link_state + (size_t)li * H);
  #pragma unroll
  for (int k = 0; k < 16; ++k) { x[k] = xa[k]; h[k] = hsrow[k]; }
  gru_cell_f2(W, x, h);
  #pragma unroll
  for (int k = 0; k < 16; ++k) hsrow[k] = h[k];
}

__global__ __launch_bounds__(256) void readout_kernel(
    const float* __restrict__ path_state, const float* __restrict__ W,
    const int* __restrict__ flag, void* __restrict__ out) {
  int p = blockIdx.x * 256 + threadIdx.x;
  if (p >= NP) return;
  const float* W1 = W;
  const float* b1 = W + 256;
  const float* W2 = W + 264;
  const float* b2 = W + 328;
  const float* W3 = W + 336;
  const float* b3 = W + 344;
  float xv[32];
  const float4* xp = (const float4*)(path_state + (size_t)p * H);
  #pragma unroll
  for (int k = 0; k < 8; ++k) {
    float4 v = xp[k];
    xv[4 * k] = v.x; xv[4 * k + 1] = v.y; xv[4 * k + 2] = v.z; xv[4 * k + 3] = v.w;
  }
  float y1[8];
  #pragma unroll
  for (int i = 0; i < 8; ++i) {
    float a = b1[i];
    #pragma unroll
    for (int k = 0; k < 32; ++k) a = fmaf(W1[i * 32 + k], xv[k], a);
    y1[i] = fmaxf(a, 0.f);
  }
  float y2[8];
  #pragma unroll
  for (int i = 0; i < 8; ++i) {
    float a = b2[i];
    #pragma unroll
    for (int k = 0; k < 8; ++k) a = fmaf(W2[i * 8 + k], y1[k], a);
    y2[i] = fmaxf(a, 0.f);
  }
  float o = b3[0];
  #pragma unroll
  for (int k = 0; k < 8; ++k) o = fmaf(W3[k], y2[k], o);
  if (*flag) ((__hip_bfloat16*)out)[p] = __float2bfloat16(o);
  else       ((float*)out)[p] = o;
}

extern "C" void kernel_launch(void* const* d_in, const int* in_sizes, int n_in,
                              void* d_out, int out_size, void* d_ws, size_t ws_size,
                              hipStream_t stream) {
  (void)in_sizes; (void)n_in; (void)out_size;
  const int* links = (const int*)d_in[0];
  const void* cap = d_in[3];
  const void* bw  = d_in[4];

  float* ws = (float*)d_ws;
  float* link_state = ws + LINK_OFF;
  float* path_state = ws + PATH_OFF;
  float* agg        = ws + AGG_OFF;   // fallback only
  unsigned short* lhi = (unsigned short*)(ws + AGG_OFF);            // gather mode
  unsigned short* llo = (unsigned short*)(ws + AGG_OFF + 160000);   // gather mode
  float* wts        = ws + WTS_OFF;
  int*   flag       = (int*)(ws + FLAG_OFF);
  int*   ibase      = (int*)(ws + INT_OFF);
  int*   counts     = ibase;
  int*   offsets    = ibase + 10000;
  int*   cursor     = ibase + 20016;
  int*   perm       = ibase + 30016;
  float* hs         = ws + HS_OFF;

  WPack wp;
  for (int i = 0; i < 8; ++i)
    wp.p[i] = (unsigned short*)(ws + PW_OFF + i * 1600);

  const bool use_gather = ws_size >= WS_NEED_FLOATS * sizeof(float);

  probe_dtype<<<1, 64, 0, stream>>>((const unsigned int*)cap, flag);

  BfSegs segs;
  const int srcidx[14] = {5, 6, 7, 8, 9, 10, 11, 12, 13, 14, 15, 16, 17, 18};
  const int offs[14]   = {0, 3072, 6144, 6240, 6336, 9408, 12480, 12576,
                          12672, 12928, 12936, 13000, 13008, 13016};
  const int lens[14]   = {3072, 3072, 96, 96, 3072, 3072, 96, 96,
                          256, 8, 64, 8, 8, 1};
  for (int i = 0; i < 14; ++i) {
    segs.s[i].src = d_in[srcidx[i]];
    segs.s[i].dstoff = offs[i];
    segs.s[i].len = lens[i];
  }
  convert_weights<<<14, 256, 0, stream>>>(segs, wp, flag, wts);
  init_states<<<(NP * H + 255) / 256, 256, 0, stream>>>(
      cap, bw, flag, link_state, lhi, llo, path_state);

  if (use_gather) {
    hipMemsetAsync(counts, 0, NL * sizeof(int), stream);
    csr_count<<<(E_TOT + 255) / 256, 256, 0, stream>>>(links, counts);
    csr_scan<<<1, 256, 0, stream>>>(counts, offsets, cursor);
    csr_fill<<<(E_TOT + 255) / 256, 256, 0, stream>>>(links, cursor, perm);

    const int path_blocks = (NP / 16 + 3) / 4;  // 1563
    for (int r = 0; r < NROUNDS; ++r) {
      const int last = (r == NROUNDS - 1);
      path_round_mfma<<<path_blocks, 256, 0, stream>>>(
          links, perm, lhi, llo, path_state, hs, wts,
          wp.p[0], wp.p[1], wp.p[2], wp.p[3], flag, d_out, !last);
      if (!last) {
        agg_link_round<<<NL / 16, 256, 0, stream>>>(
            offsets, hs, link_state, lhi, llo,
            wts + 6336, wp.p[4], wp.p[5], wp.p[6], wp.p[7]);
      }
    }
  } else {
    for (int r = 0; r < NROUNDS; ++r) {
      const int last = (r == NROUNDS - 1);
      if (!last) hipMemsetAsync(agg, 0, NL * H * sizeof(float), stream);
      path_round_atomic<<<(NP + 63) / 64, 64, 0, stream>>>(
          links, link_state, path_state, agg, wts, !last);
      if (!last)
        link_round_scalar<<<(NL + 63) / 64, 64, 0, stream>>>(agg, link_state, wts + 6336);
    }
    readout_kernel<<<(NP + 255) / 256, 256, 0, stream>>>(
        path_state, wts + 12672, flag, d_out);
  }
}

// Round 13
// 774.690 us; speedup vs baseline: 2.9645x; 1.1995x over previous
//
#include <hip/hip_runtime.h>
#include <hip/hip_bf16.h>

#define NL 10000
#define NP 100000
#define PLEN 8
#define H 32
#define NROUNDS 8
#define E_TOT (NP * PLEN)

typedef float f2 __attribute__((ext_vector_type(2)));
typedef float f4 __attribute__((ext_vector_type(4)));
typedef short bh8 __attribute__((ext_vector_type(8)));

// ---------- ws layout (float offsets) ----------
#define LINK_OFF   0          // 320000 fp32 link_state
#define PATH_OFF   320000     // 3200000
#define AGG_OFF    3520000    // 320000: gather mode reuses as LHI(160000)+LLO(160000)
#define WTS_OFF    3840000    // 13345 fp32 weights
#define PW_OFF     3853400    // 8 regions x 1600 floats (ushort[3072] each)
#define FLAG_OFF   3869000
#define INT_OFF    3870000    // ints: counts | offsets@10000 | cursor@20016 | perm@30016 (800000)
#define HS_OFF     4700032
#define WS_NEED_FLOATS (HS_OFF + (size_t)E_TOT * H)

#define LOG2E 1.44269504f

__device__ __forceinline__ float bf2f(unsigned short u) {
  union { unsigned int i; float f; } v; v.i = ((unsigned int)u) << 16; return v.f;
}
__device__ __forceinline__ float fast_exp2(float x) {
#if __has_builtin(__builtin_amdgcn_exp2f)
  return __builtin_amdgcn_exp2f(x);
#else
  return __expf(x * 0.69314718f);
#endif
}
__device__ __forceinline__ float fast_rcp(float x) {
#if __has_builtin(__builtin_amdgcn_rcpf)
  return __builtin_amdgcn_rcpf(x);
#else
  return 1.f / x;
#endif
}
__device__ __forceinline__ float fast_sigm(float x) {
  return fast_rcp(1.f + fast_exp2(-LOG2E * x));
}
__device__ __forceinline__ float fast_tanh2(float x) {
  return 1.f - 2.f * fast_rcp(1.f + fast_exp2((2.f * LOG2E) * x));
}
__device__ __forceinline__ float loadf(const void* p, long i, bool bf) {
  return bf ? bf2f(((const unsigned short*)p)[i]) : ((const float*)p)[i];
}

// split 8 fp32 into bf16 hi + bf16 lo (residual), trunc rounding
__device__ __forceinline__ void split8(f4 a, f4 b, bh8& hi, bh8& lo) {
  #pragma unroll
  for (int i = 0; i < 4; ++i) {
    unsigned ua = __float_as_uint(a[i]);
    float hfa = __uint_as_float(ua & 0xffff0000u);
    hi[i] = (short)(ua >> 16);
    lo[i] = (short)(__float_as_uint(a[i] - hfa) >> 16);
    unsigned ub = __float_as_uint(b[i]);
    float hfb = __uint_as_float(ub & 0xffff0000u);
    hi[4 + i] = (short)(ub >> 16);
    lo[4 + i] = (short)(__float_as_uint(b[i] - hfb) >> 16);
  }
}

// ---------- dtype probe ----------
__global__ void probe_dtype(const unsigned int* __restrict__ cap_words,
                            int* __restrict__ flag) {
  int lane = threadIdx.x;
  int c = 0;
  #pragma unroll
  for (int i = 0; i < 4; ++i) {
    unsigned int b = (cap_words[lane * 4 + i] >> 8) & 0xFF;
    if (b >= 0x30 && b < 0x40) ++c;
  }
  #pragma unroll
  for (int d = 32; d > 0; d >>= 1) c += __shfl_down(c, d);
  if (lane == 0) *flag = (c > 128) ? 1 : 0;
}

// ---------- scalar GRU cell (fallback path only) ----------
__device__ __forceinline__ void gru_cell_f2(const float* __restrict__ W,
                                            const f2 x[16], f2 h[16]) {
  const f2* Wih = (const f2*)W;
  const f2* Whh = (const f2*)(W + 3072);
  const float* bih = W + 6144;
  const float* bhh = W + 6240;
  f2 hn[16];
  #pragma unroll
  for (int jj = 0; jj < 16; ++jj) {
    #pragma unroll
    for (int s = 0; s < 2; ++s) {
      const int j = 2 * jj + s;
      f2 ar = {0.f, 0.f}, az = {0.f, 0.f}, an = {0.f, 0.f}, ah = {0.f, 0.f};
      #pragma unroll
      for (int k = 0; k < 16; ++k) {
        ar = __builtin_elementwise_fma(Wih[j * 16 + k], x[k], ar);
        ar = __builtin_elementwise_fma(Whh[j * 16 + k], h[k], ar);
        az = __builtin_elementwise_fma(Wih[(H + j) * 16 + k], x[k], az);
        az = __builtin_elementwise_fma(Whh[(H + j) * 16 + k], h[k], az);
        an = __builtin_elementwise_fma(Wih[(2 * H + j) * 16 + k], x[k], an);
        ah = __builtin_elementwise_fma(Whh[(2 * H + j) * 16 + k], h[k], ah);
      }
      float r = fast_sigm(ar.x + ar.y + bih[j] + bhh[j]);
      float z = fast_sigm(az.x + az.y + bih[H + j] + bhh[H + j]);
      float n = fast_tanh2(an.x + an.y + bih[2 * H + j] +
                           r * (ah.x + ah.y + bhh[2 * H + j]));
      float hold = (s == 0) ? h[jj].x : h[jj].y;
      float hv = n + z * (hold - n);
      if (s == 0) hn[jj].x = hv; else hn[jj].y = hv;
    }
  }
  #pragma unroll
  for (int k = 0; k < 16; ++k) h[k] = hn[k];
}

// ---------- weight conversion (+ hi/lo bf16 splits of all 4 GRU matrices) ----------
struct BfSeg { const void* src; int dstoff; int len; };
struct BfSegs { BfSeg s[14]; };
struct WPack { unsigned short* p[8]; };

__global__ void convert_weights(BfSegs segs, WPack wp, const int* __restrict__ flag,
                                float* __restrict__ dst) {
  const bool bf = (*flag != 0);
  const int si = blockIdx.x;
  const void* p = segs.s[si].src;
  const int off = segs.s[si].dstoff, len = segs.s[si].len;
  int hix = -1;
  if (si == 0) hix = 0; else if (si == 1) hix = 2;
  else if (si == 4) hix = 4; else if (si == 5) hix = 6;
  for (int i = threadIdx.x; i < len; i += blockDim.x) {
    float f = loadf(p, i, bf);
    dst[off + i] = f;
    if (hix >= 0) {
      unsigned u = __float_as_uint(f);
      float fh = __uint_as_float(u & 0xffff0000u);
      wp.p[hix][i] = (unsigned short)(u >> 16);
      wp.p[hix + 1][i] = (unsigned short)(__float_as_uint(f - fh) >> 16);
    }
  }
}

__global__ void init_states(const void* __restrict__ cap,
                            const void* __restrict__ bw,
                            const int* __restrict__ flag,
                            float* __restrict__ link_state,
                            unsigned short* __restrict__ lhi,
                            unsigned short* __restrict__ llo,
                            float* __restrict__ path_state) {
  const bool bf = (*flag != 0);
  int i = blockIdx.x * blockDim.x + threadIdx.x;
  if (i < NP * H) path_state[i] = ((i & (H - 1)) == 0) ? loadf(bw, i >> 5, bf) : 0.f;
  if (i < NL * H) {
    float v = ((i & (H - 1)) == 0) ? loadf(cap, i >> 5, bf) : 0.f;
    link_state[i] = v;
    unsigned u = __float_as_uint(v);
    float fh = __uint_as_float(u & 0xffff0000u);
    lhi[i] = (unsigned short)(u >> 16);
    llo[i] = (unsigned short)(__float_as_uint(v - fh) >> 16);
  }
}

// ---------- CSR build ----------
__global__ void csr_count(const int* __restrict__ links, int* __restrict__ counts) {
  int e = blockIdx.x * blockDim.x + threadIdx.x;
  if (e < E_TOT) atomicAdd(&counts[links[e]], 1);
}

__global__ __launch_bounds__(256) void csr_scan(const int* __restrict__ counts,
                                                int* __restrict__ offsets,
                                                int* __restrict__ cursor) {
  __shared__ int part[256];
  const int t = threadIdx.x;
  const int base = t * 40;
  int s = 0;
  for (int i = 0; i < 40; ++i) {
    int idx = base + i;
    if (idx < NL) s += counts[idx];
  }
  part[t] = s;
  __syncthreads();
  for (int d = 1; d < 256; d <<= 1) {
    int v = (t >= d) ? part[t - d] : 0;
    __syncthreads();
    part[t] += v;
    __syncthreads();
  }
  int run = (t > 0) ? part[t - 1] : 0;
  for (int i = 0; i < 40; ++i) {
    int idx = base + i;
    if (idx < NL) {
      offsets[idx] = run;
      cursor[idx] = run;
      run += counts[idx];
    }
  }
  if (t == 255) offsets[NL] = run;
}

// perm[e] = CSR slot of edge e — path kernel scatters messages into CSR order
__global__ void csr_fill(const int* __restrict__ links, int* __restrict__ cursor,
                         int* __restrict__ perm) {
  int e = blockIdx.x * blockDim.x + threadIdx.x;
  if (e < E_TOT) {
    int l = links[e];
    int pos = atomicAdd(&cursor[l], 1);
    perm[e] = pos;
  }
}

// ---------- MFMA path round: block=256 = 4 waves, each wave = 16 paths ----------
// fp32-exact via hi/lo splits of BOTH weights and states (lo*lo dropped ~2^-17).
// Template: LAST=0 (rounds 0-6) stores hs + path_state, NO readout code (keeps
// VGPR ~104); LAST=1 (round 7) skips perm/hs/path_state, runs fused readout —
// its higher VGPR count (~132) is paid on one dispatch only. (Round-12 lesson:
// a single fused kernel paid 132 VGPRs on every round, 16%->9% occupancy.)
template <int LAST>
__global__ __launch_bounds__(256) void path_round_mfma(
    const int* __restrict__ links, const int* __restrict__ perm,
    const unsigned short* __restrict__ lhi, const unsigned short* __restrict__ llo,
    float* __restrict__ path_state, float* __restrict__ hs,
    const float* __restrict__ W,
    const unsigned short* __restrict__ wih_hi, const unsigned short* __restrict__ wih_lo,
    const unsigned short* __restrict__ whh_hi, const unsigned short* __restrict__ whh_lo,
    const int* __restrict__ flag, void* __restrict__ out) {
  __shared__ float lds_all[4 * 16 * 36];
  const int wv = threadIdx.x >> 6;
  const int tile = blockIdx.x * 4 + wv;
  if (tile >= NP / 16) return;
  const int p0 = tile * 16;
  const int lane = threadIdx.x & 63;
  const int c = lane & 15, q = lane >> 4, m = c;
  float* lds = lds_all + wv * (16 * 36);

  bh8 wihH[6], wihL[6], whhH[6], whhL[6];
  #pragma unroll
  for (int tn = 0; tn < 6; ++tn) {
    size_t o = (size_t)(tn * 16 + c) * H + q * 8;
    wihH[tn] = *(const bh8*)(wih_hi + o);
    wihL[tn] = *(const bh8*)(wih_lo + o);
    whhH[tn] = *(const bh8*)(whh_hi + o);
    whhL[tn] = *(const bh8*)(whh_lo + o);
  }
  const float* bih = W + 6144;
  const float* bhh = W + 6240;
  float b_r[2], b_z[2], b_in[2], b_hn[2];
  #pragma unroll
  for (int u2 = 0; u2 < 2; ++u2) {
    int u = u2 * 16 + c;
    b_r[u2] = bih[u] + bhh[u];
    b_z[u2] = bih[32 + u] + bhh[32 + u];
    b_in[u2] = bih[64 + u];
    b_hn[u2] = bhh[64 + u];
  }
  float hC[2][4];
  #pragma unroll
  for (int u2 = 0; u2 < 2; ++u2)
    #pragma unroll
    for (int rg = 0; rg < 4; ++rg)
      hC[u2][rg] = path_state[(size_t)(p0 + q * 4 + rg) * H + u2 * 16 + c];
  f4 hfa = *(const f4*)(path_state + (size_t)(p0 + m) * H + q * 8);
  f4 hfb = *(const f4*)(path_state + (size_t)(p0 + m) * H + q * 8 + 4);
  bh8 hhi, hlo;
  split8(hfa, hfb, hhi, hlo);
  int lk[PLEN], pm[PLEN];
  {
    const int4* lp = (const int4*)(links + (size_t)(p0 + m) * PLEN);
    int4 a = lp[0], b = lp[1];
    lk[0] = a.x; lk[1] = a.y; lk[2] = a.z; lk[3] = a.w;
    lk[4] = b.x; lk[5] = b.y; lk[6] = b.z; lk[7] = b.w;
    if (!LAST) {
      const int4* qp = (const int4*)(perm + (size_t)(p0 + m) * PLEN);
      int4 e = qp[0], f = qp[1];
      pm[0] = e.x; pm[1] = e.y; pm[2] = e.z; pm[3] = e.w;
      pm[4] = f.x; pm[5] = f.y; pm[6] = f.z; pm[7] = f.w;
    }
  }
  bh8 xhi = *(const bh8*)(lhi + (size_t)lk[0] * H + q * 8);
  bh8 xlo = *(const bh8*)(llo + (size_t)lk[0] * H + q * 8);
  const f4 z4 = {0.f, 0.f, 0.f, 0.f};

  #pragma unroll 1
  for (int t = 0; t < PLEN; ++t) {
    bh8 xnhi, xnlo;
    if (t + 1 < PLEN) {
      xnhi = *(const bh8*)(lhi + (size_t)lk[t + 1] * H + q * 8);
      xnlo = *(const bh8*)(llo + (size_t)lk[t + 1] * H + q * 8);
    }
    f4 aR[2], aZ[2], aI[2], aHn[2];
    #pragma unroll
    for (int u2 = 0; u2 < 2; ++u2) {
      f4 a = z4;
      a = __builtin_amdgcn_mfma_f32_16x16x32_bf16(xhi, wihH[u2], a, 0, 0, 0);
      a = __builtin_amdgcn_mfma_f32_16x16x32_bf16(hhi, whhH[u2], a, 0, 0, 0);
      a = __builtin_amdgcn_mfma_f32_16x16x32_bf16(xlo, wihH[u2], a, 0, 0, 0);
      a = __builtin_amdgcn_mfma_f32_16x16x32_bf16(hlo, whhH[u2], a, 0, 0, 0);
      a = __builtin_amdgcn_mfma_f32_16x16x32_bf16(xhi, wihL[u2], a, 0, 0, 0);
      a = __builtin_amdgcn_mfma_f32_16x16x32_bf16(hhi, whhL[u2], a, 0, 0, 0);
      aR[u2] = a;
      f4 b = z4;
      b = __builtin_amdgcn_mfma_f32_16x16x32_bf16(xhi, wihH[2 + u2], b, 0, 0, 0);
      b = __builtin_amdgcn_mfma_f32_16x16x32_bf16(hhi, whhH[2 + u2], b, 0, 0, 0);
      b = __builtin_amdgcn_mfma_f32_16x16x32_bf16(xlo, wihH[2 + u2], b, 0, 0, 0);
      b = __builtin_amdgcn_mfma_f32_16x16x32_bf16(hlo, whhH[2 + u2], b, 0, 0, 0);
      b = __builtin_amdgcn_mfma_f32_16x16x32_bf16(xhi, wihL[2 + u2], b, 0, 0, 0);
      b = __builtin_amdgcn_mfma_f32_16x16x32_bf16(hhi, whhL[2 + u2], b, 0, 0, 0);
      aZ[u2] = b;
      f4 ci = z4;
      ci = __builtin_amdgcn_mfma_f32_16x16x32_bf16(xhi, wihH[4 + u2], ci, 0, 0, 0);
      ci = __builtin_amdgcn_mfma_f32_16x16x32_bf16(xlo, wihH[4 + u2], ci, 0, 0, 0);
      ci = __builtin_amdgcn_mfma_f32_16x16x32_bf16(xhi, wihL[4 + u2], ci, 0, 0, 0);
      aI[u2] = ci;
      f4 ch = z4;
      ch = __builtin_amdgcn_mfma_f32_16x16x32_bf16(hhi, whhH[4 + u2], ch, 0, 0, 0);
      ch = __builtin_amdgcn_mfma_f32_16x16x32_bf16(hlo, whhH[4 + u2], ch, 0, 0, 0);
      ch = __builtin_amdgcn_mfma_f32_16x16x32_bf16(hhi, whhL[4 + u2], ch, 0, 0, 0);
      aHn[u2] = ch;
    }
    #pragma unroll
    for (int u2 = 0; u2 < 2; ++u2)
      #pragma unroll
      for (int rg = 0; rg < 4; ++rg) {
        float rr = fast_sigm(aR[u2][rg] + b_r[u2]);
        float zz = fast_sigm(aZ[u2][rg] + b_z[u2]);
        float nn = fast_tanh2(fmaf(rr, aHn[u2][rg] + b_hn[u2], aI[u2][rg] + b_in[u2]));
        float hv = fmaf(zz, hC[u2][rg] - nn, nn);
        hC[u2][rg] = hv;
        lds[(q * 4 + rg) * 36 + u2 * 16 + c] = hv;
      }
    __builtin_amdgcn_wave_barrier();
    __builtin_amdgcn_s_waitcnt(0xC07F);  // lgkmcnt(0)
    f4 ha = *(const f4*)(lds + m * 36 + q * 8);
    f4 hb = *(const f4*)(lds + m * 36 + q * 8 + 4);
    __builtin_amdgcn_wave_barrier();
    if (!LAST) {
      float* hp = hs + (size_t)pm[t] * H + q * 8;  // CSR-permuted row
      *(f4*)hp = ha;
      *(f4*)(hp + 4) = hb;
    }
    if (t + 1 < PLEN) {
      split8(ha, hb, hhi, hlo);
      xhi = xnhi; xlo = xnlo;
    } else if (LAST) {
      // ---- fused readout MLP: lane holds h[q*8..q*8+7] of path p0+m
      const float* RW = W + 12672;  // W1[256] b1[8] W2[64] b2[8] W3[8] b3[1]
      float part[8];
      #pragma unroll
      for (int i = 0; i < 8; ++i) {
        const f4* w4 = (const f4*)(RW + i * 32 + q * 8);
        f4 wa = w4[0], wb = w4[1];
        part[i] = wa[0] * ha[0] + wa[1] * ha[1] + wa[2] * ha[2] + wa[3] * ha[3]
                + wb[0] * hb[0] + wb[1] * hb[1] + wb[2] * hb[2] + wb[3] * hb[3];
      }
      #pragma unroll
      for (int i = 0; i < 8; ++i) {
        part[i] += __shfl_xor(part[i], 16);
        part[i] += __shfl_xor(part[i], 32);
      }
      if (q == 0) {
        float y1[8], y2[8];
        #pragma unroll
        for (int i = 0; i < 8; ++i) y1[i] = fmaxf(part[i] + RW[256 + i], 0.f);
        #pragma unroll
        for (int i = 0; i < 8; ++i) {
          float a = RW[328 + i];
          #pragma unroll
          for (int k = 0; k < 8; ++k) a = fmaf(RW[264 + i * 8 + k], y1[k], a);
          y2[i] = fmaxf(a, 0.f);
        }
        float o = RW[344];
        #pragma unroll
        for (int k = 0; k < 8; ++k) o = fmaf(RW[336 + k], y2[k], o);
        if (*flag) ((__hip_bfloat16*)out)[p0 + m] = __float2bfloat16(o);
        else       ((float*)out)[p0 + m] = o;
      }
    } else {
      float* pp = path_state + (size_t)(p0 + m) * H + q * 8;
      *(f4*)pp = ha;
      *(f4*)(pp + 4) = hb;
    }
  }
}

// ---------- fused aggregation + link GRU: 1 block = 16 links ----------
// hs is CSR-ordered: link l's messages occupy rows [offsets[l], offsets[l+1]).
__global__ __launch_bounds__(256) void agg_link_round(
    const int* __restrict__ offsets,
    const float* __restrict__ hs, float* __restrict__ link_state,
    unsigned short* __restrict__ lhi, unsigned short* __restrict__ llo,
    const float* __restrict__ W,
    const unsigned short* __restrict__ wih_hi, const unsigned short* __restrict__ wih_lo,
    const unsigned short* __restrict__ whh_hi, const unsigned short* __restrict__ whh_lo) {
  __shared__ float aggL[16 * 36];
  const int l0 = blockIdx.x * 16;
  const int wv = threadIdx.x >> 6;
  const int lane = threadIdx.x & 63;
  #pragma unroll 1
  for (int s = 0; s < 4; ++s) {
    const int li = wv * 4 + s;
    const int l = l0 + li;
    const int beg = offsets[l], end = offsets[l + 1];
    const f4* base4 = (const f4*)(hs + (size_t)beg * H);
    const int nvec = (end - beg) * (H / 4);
    f4 a0 = {0.f, 0.f, 0.f, 0.f}, a1 = {0.f, 0.f, 0.f, 0.f};
    int i = lane;
    for (; i + 64 < nvec; i += 128) {
      a0 += base4[i];
      a1 += base4[i + 64];
    }
    if (i < nvec) a0 += base4[i];
    a0 += a1;
    #pragma unroll
    for (int d = 32; d >= 8; d >>= 1) {
      #pragma unroll
      for (int k = 0; k < 4; ++k) a0[k] += __shfl_xor(a0[k], d);
    }
    if (lane < 8) *(f4*)(aggL + li * 36 + 4 * lane) = a0;
  }
  __syncthreads();
  if (threadIdx.x >= 64) return;
  // phase 2: wave 0 does a 16-link GRU step (full hi/lo weights)
  const int c = lane & 15, q = lane >> 4, m = c;
  bh8 wihH[6], wihL[6], whhH[6], whhL[6];
  #pragma unroll
  for (int tn = 0; tn < 6; ++tn) {
    size_t o = (size_t)(tn * 16 + c) * H + q * 8;
    wihH[tn] = *(const bh8*)(wih_hi + o);
    wihL[tn] = *(const bh8*)(wih_lo + o);
    whhH[tn] = *(const bh8*)(whh_hi + o);
    whhL[tn] = *(const bh8*)(whh_lo + o);
  }
  const float* bih = W + 6144;
  const float* bhh = W + 6240;
  float b_r[2], b_z[2], b_in[2], b_hn[2];
  #pragma unroll
  for (int u2 = 0; u2 < 2; ++u2) {
    int u = u2 * 16 + c;
    b_r[u2] = bih[u] + bhh[u];
    b_z[u2] = bih[32 + u] + bhh[32 + u];
    b_in[u2] = bih[64 + u];
    b_hn[u2] = bhh[64 + u];
  }
  float hC[2][4];
  #pragma unroll
  for (int u2 = 0; u2 < 2; ++u2)
    #pragma unroll
    for (int rg = 0; rg < 4; ++rg)
      hC[u2][rg] = link_state[(size_t)(l0 + q * 4 + rg) * H + u2 * 16 + c];
  f4 xa = *(const f4*)(aggL + m * 36 + q * 8);
  f4 xb = *(const f4*)(aggL + m * 36 + q * 8 + 4);
  f4 hfa = *(const f4*)(link_state + (size_t)(l0 + m) * H + q * 8);
  f4 hfb = *(const f4*)(link_state + (size_t)(l0 + m) * H + q * 8 + 4);
  bh8 xhi, xlo, hhi, hlo;
  split8(xa, xb, xhi, xlo);
  split8(hfa, hfb, hhi, hlo);
  const f4 z4 = {0.f, 0.f, 0.f, 0.f};
  f4 aR[2], aZ[2], aI[2], aHn[2];
  #pragma unroll
  for (int u2 = 0; u2 < 2; ++u2) {
    f4 a = z4;
    a = __builtin_amdgcn_mfma_f32_16x16x32_bf16(xhi, wihH[u2], a, 0, 0, 0);
    a = __builtin_amdgcn_mfma_f32_16x16x32_bf16(hhi, whhH[u2], a, 0, 0, 0);
    a = __builtin_amdgcn_mfma_f32_16x16x32_bf16(xlo, wihH[u2], a, 0, 0, 0);
    a = __builtin_amdgcn_mfma_f32_16x16x32_bf16(hlo, whhH[u2], a, 0, 0, 0);
    a = __builtin_amdgcn_mfma_f32_16x16x32_bf16(xhi, wihL[u2], a, 0, 0, 0);
    a = __builtin_amdgcn_mfma_f32_16x16x32_bf16(hhi, whhL[u2], a, 0, 0, 0);
    aR[u2] = a;
    f4 b = z4;
    b = __builtin_amdgcn_mfma_f32_16x16x32_bf16(xhi, wihH[2 + u2], b, 0, 0, 0);
    b = __builtin_amdgcn_mfma_f32_16x16x32_bf16(hhi, whhH[2 + u2], b, 0, 0, 0);
    b = __builtin_amdgcn_mfma_f32_16x16x32_bf16(xlo, wihH[2 + u2], b, 0, 0, 0);
    b = __builtin_amdgcn_mfma_f32_16x16x32_bf16(hlo, whhH[2 + u2], b, 0, 0, 0);
    b = __builtin_amdgcn_mfma_f32_16x16x32_bf16(xhi, wihL[2 + u2], b, 0, 0, 0);
    b = __builtin_amdgcn_mfma_f32_16x16x32_bf16(hhi, whhL[2 + u2], b, 0, 0, 0);
    aZ[u2] = b;
    f4 ci = z4;
    ci = __builtin_amdgcn_mfma_f32_16x16x32_bf16(xhi, wihH[4 + u2], ci, 0, 0, 0);
    ci = __builtin_amdgcn_mfma_f32_16x16x32_bf16(xlo, wihH[4 + u2], ci, 0, 0, 0);
    ci = __builtin_amdgcn_mfma_f32_16x16x32_bf16(xhi, wihL[4 + u2], ci, 0, 0, 0);
    aI[u2] = ci;
    f4 ch = z4;
    ch = __builtin_amdgcn_mfma_f32_16x16x32_bf16(hhi, whhH[4 + u2], ch, 0, 0, 0);
    ch = __builtin_amdgcn_mfma_f32_16x16x32_bf16(hlo, whhH[4 + u2], ch, 0, 0, 0);
    ch = __builtin_amdgcn_mfma_f32_16x16x32_bf16(hhi, whhL[4 + u2], ch, 0, 0, 0);
    aHn[u2] = ch;
  }
  #pragma unroll
  for (int u2 = 0; u2 < 2; ++u2)
    #pragma unroll
    for (int rg = 0; rg < 4; ++rg) {
      float rr = fast_sigm(aR[u2][rg] + b_r[u2]);
      float zz = fast_sigm(aZ[u2][rg] + b_z[u2]);
      float nn = fast_tanh2(fmaf(rr, aHn[u2][rg] + b_hn[u2], aI[u2][rg] + b_in[u2]));
      float hv = fmaf(zz, hC[u2][rg] - nn, nn);
      size_t idx = (size_t)(l0 + q * 4 + rg) * H + u2 * 16 + c;
      link_state[idx] = hv;
      unsigned u = __float_as_uint(hv);
      float fh = __uint_as_float(u & 0xffff0000u);
      lhi[idx] = (unsigned short)(u >> 16);
      llo[idx] = (unsigned short)(__float_as_uint(hv - fh) >> 16);
    }
}

// ---------- legacy fallback kernels (ws too small) ----------
__global__ __launch_bounds__(64) void path_round_atomic(
    const int* __restrict__ links, const float* __restrict__ link_state,
    float* __restrict__ path_state, float* __restrict__ agg,
    const float* __restrict__ W, int do_scatter) {
  int p = blockIdx.x * 64 + threadIdx.x;
  if (p >= NP) return;
  f2 h[16];
  const f2* ps2 = (const f2*)(path_state + (size_t)p * H);
  #pragma unroll
  for (int k = 0; k < 16; ++k) h[k] = ps2[k];
  int lk[PLEN];
  const int4* lp = (const int4*)(links + (size_t)p * PLEN);
  int4 la = lp[0], lb = lp[1];
  lk[0] = la.x; lk[1] = la.y; lk[2] = la.z; lk[3] = la.w;
  lk[4] = lb.x; lk[5] = lb.y; lk[6] = lb.z; lk[7] = lb.w;
  #pragma unroll 1
  for (int t = 0; t < PLEN; ++t) {
    const f2* xs = (const f2*)(link_state + (size_t)lk[t] * H);
    f2 x[16];
    #pragma unroll
    for (int k = 0; k < 16; ++k) x[k] = xs[k];
    gru_cell_f2(W, x, h);
    if (do_scatter) {
      float* dst = agg + (size_t)lk[t] * H;
      #pragma unroll
      for (int k = 0; k < 16; ++k) {
        unsafeAtomicAdd(dst + 2 * k, h[k].x);
        unsafeAtomicAdd(dst + 2 * k + 1, h[k].y);
      }
    }
  }
  f2* po = (f2*)(path_state + (size_t)p * H);
  #pragma unroll
  for (int k = 0; k < 16; ++k) po[k] = h[k];
}

__global__ __launch_bounds__(64) void link_round_scalar(
    const float* __restrict__ agg, float* __restrict__ link_state,
    const float* __restrict__ W) {
  int li = blockIdx.x * 64 + threadIdx.x;
  if (li >= NL) return;
  f2 x[16], h[16];
  const f2* xa = (const f2*)(agg + (size_t)li * H);
  f2* hsrow = (f2*)(link_state + (size_t)li * H);
  #pragma unroll
  for (int k = 0; k < 16; ++k) { x[k] = xa[k]; h[k] = hsrow[k]; }
  gru_cell_f2(W, x, h);
  #pragma unroll
  for (int k = 0; k < 16; ++k) hsrow[k] = h[k];
}

__global__ __launch_bounds__(256) void readout_kernel(
    const float* __restrict__ path_state, const float* __restrict__ W,
    const int* __restrict__ flag, void* __restrict__ out) {
  int p = blockIdx.x * 256 + threadIdx.x;
  if (p >= NP) return;
  const float* W1 = W;
  const float* b1 = W + 256;
  const float* W2 = W + 264;
  const float* b2 = W + 328;
  const float* W3 = W + 336;
  const float* b3 = W + 344;
  float xv[32];
  const float4* xp = (const float4*)(path_state + (size_t)p * H);
  #pragma unroll
  for (int k = 0; k < 8; ++k) {
    float4 v = xp[k];
    xv[4 * k] = v.x; xv[4 * k + 1] = v.y; xv[4 * k + 2] = v.z; xv[4 * k + 3] = v.w;
  }
  float y1[8];
  #pragma unroll
  for (int i = 0; i < 8; ++i) {
    float a = b1[i];
    #pragma unroll
    for (int k = 0; k < 32; ++k) a = fmaf(W1[i * 32 + k], xv[k], a);
    y1[i] = fmaxf(a, 0.f);
  }
  float y2[8];
  #pragma unroll
  for (int i = 0; i < 8; ++i) {
    float a = b2[i];
    #pragma unroll
    for (int k = 0; k < 8; ++k) a = fmaf(W2[i * 8 + k], y1[k], a);
    y2[i] = fmaxf(a, 0.f);
  }
  float o = b3[0];
  #pragma unroll
  for (int k = 0; k < 8; ++k) o = fmaf(W3[k], y2[k], o);
  if (*flag) ((__hip_bfloat16*)out)[p] = __float2bfloat16(o);
  else       ((float*)out)[p] = o;
}

extern "C" void kernel_launch(void* const* d_in, const int* in_sizes, int n_in,
                              void* d_out, int out_size, void* d_ws, size_t ws_size,
                              hipStream_t stream) {
  (void)in_sizes; (void)n_in; (void)out_size;
  const int* links = (const int*)d_in[0];
  const void* cap = d_in[3];
  const void* bw  = d_in[4];

  float* ws = (float*)d_ws;
  float* link_state = ws + LINK_OFF;
  float* path_state = ws + PATH_OFF;
  float* agg        = ws + AGG_OFF;   // fallback only
  unsigned short* lhi = (unsigned short*)(ws + AGG_OFF);            // gather mode
  unsigned short* llo = (unsigned short*)(ws + AGG_OFF + 160000);   // gather mode
  float* wts        = ws + WTS_OFF;
  int*   flag       = (int*)(ws + FLAG_OFF);
  int*   ibase      = (int*)(ws + INT_OFF);
  int*   counts     = ibase;
  int*   offsets    = ibase + 10000;
  int*   cursor     = ibase + 20016;
  int*   perm       = ibase + 30016;
  float* hs         = ws + HS_OFF;

  WPack wp;
  for (int i = 0; i < 8; ++i)
    wp.p[i] = (unsigned short*)(ws + PW_OFF + i * 1600);

  const bool use_gather = ws_size >= WS_NEED_FLOATS * sizeof(float);

  probe_dtype<<<1, 64, 0, stream>>>((const unsigned int*)cap, flag);

  BfSegs segs;
  const int srcidx[14] = {5, 6, 7, 8, 9, 10, 11, 12, 13, 14, 15, 16, 17, 18};
  const int offs[14]   = {0, 3072, 6144, 6240, 6336, 9408, 12480, 12576,
                          12672, 12928, 12936, 13000, 13008, 13016};
  const int lens[14]   = {3072, 3072, 96, 96, 3072, 3072, 96, 96,
                          256, 8, 64, 8, 8, 1};
  for (int i = 0; i < 14; ++i) {
    segs.s[i].src = d_in[srcidx[i]];
    segs.s[i].dstoff = offs[i];
    segs.s[i].len = lens[i];
  }
  convert_weights<<<14, 256, 0, stream>>>(segs, wp, flag, wts);
  init_states<<<(NP * H + 255) / 256, 256, 0, stream>>>(
      cap, bw, flag, link_state, lhi, llo, path_state);

  if (use_gather) {
    hipMemsetAsync(counts, 0, NL * sizeof(int), stream);
    csr_count<<<(E_TOT + 255) / 256, 256, 0, stream>>>(links, counts);
    csr_scan<<<1, 256, 0, stream>>>(counts, offsets, cursor);
    csr_fill<<<(E_TOT + 255) / 256, 256, 0, stream>>>(links, cursor, perm);

    const int path_blocks = (NP / 16 + 3) / 4;  // 1563
    for (int r = 0; r < NROUNDS - 1; ++r) {
      path_round_mfma<0><<<path_blocks, 256, 0, stream>>>(
          links, perm, lhi, llo, path_state, hs, wts,
          wp.p[0], wp.p[1], wp.p[2], wp.p[3], flag, d_out);
      agg_link_round<<<NL / 16, 256, 0, stream>>>(
          offsets, hs, link_state, lhi, llo,
          wts + 6336, wp.p[4], wp.p[5], wp.p[6], wp.p[7]);
    }
    path_round_mfma<1><<<path_blocks, 256, 0, stream>>>(
        links, perm, lhi, llo, path_state, hs, wts,
        wp.p[0], wp.p[1], wp.p[2], wp.p[3], flag, d_out);
  } else {
    for (int r = 0; r < NROUNDS; ++r) {
      const int last = (r == NROUNDS - 1);
      if (!last) hipMemsetAsync(agg, 0, NL * H * sizeof(float), stream);
      path_round_atomic<<<(NP + 63) / 64, 64, 0, stream>>>(
          links, link_state, path_state, agg, wts, !last);
      if (!last)
        link_round_scalar<<<(NL + 63) / 64, 64, 0, stream>>>(agg, link_state, wts + 6336);
    }
    readout_kernel<<<(NP + 255) / 256, 256, 0, stream>>>(
        path_state, wts + 12672, flag, d_out);
  }
}